// Round 1
// baseline (470.234 us; speedup 1.0000x reference)
//
#include <hip/hip_runtime.h>
#include <cstdint>
#include <cstddef>

#define N_NODES 30000
#define N_EDGES 480000
#define N_EDGES_SL (N_EDGES + N_NODES) // 510000
#define IN_CH 128
#define HEADS1 5
#define C1 64
#define D1 (HEADS1 * C1) // 320
#define OUT_CH 64
#define PE_CNT 100000
#define NEG_SLOPE 0.2f

static __device__ __forceinline__ float leaky(float x) {
    return x > 0.f ? x : NEG_SLOPE * x;
}

// ---------------- utility ----------------
__global__ void zero_i32(int* __restrict__ p, int n) {
    int i = blockIdx.x * blockDim.x + threadIdx.x;
    if (i < n) p[i] = 0;
}

// ---------------- CSR build (counting sort by dst) ----------------
__global__ void count_dst(const int* __restrict__ edge, int* __restrict__ cnt) {
    int e = blockIdx.x * blockDim.x + threadIdx.x;
    if (e >= N_EDGES_SL) return;
    int d = (e < N_EDGES) ? edge[N_EDGES + e] : (e - N_EDGES);
    atomicAdd(&cnt[d], 1);
}

__global__ __launch_bounds__(1024) void scan30000(const int* __restrict__ cnt,
                                                  int* __restrict__ row_ptr) {
    __shared__ int buf[1024];
    __shared__ int carry;
    int tid = threadIdx.x;
    if (tid == 0) carry = 0;
    __syncthreads();
    for (int base = 0; base < N_NODES; base += 1024) {
        int i = base + tid;
        int v = (i < N_NODES) ? cnt[i] : 0;
        buf[tid] = v;
        __syncthreads();
        for (int off = 1; off < 1024; off <<= 1) {
            int t = (tid >= off) ? buf[tid - off] : 0;
            __syncthreads();
            buf[tid] += t;
            __syncthreads();
        }
        int inc = buf[tid]; // inclusive scan of this chunk
        int c = carry;
        if (i < N_NODES) row_ptr[i] = c + inc - v; // exclusive
        __syncthreads();
        if (tid == 1023) carry = c + inc;
        __syncthreads();
    }
    if (tid == 0) row_ptr[N_NODES] = carry;
}

__global__ void scatter_edges(const int* __restrict__ edge, const int* __restrict__ row_ptr,
                              int* __restrict__ cursor, int* __restrict__ esrc) {
    int e = blockIdx.x * blockDim.x + threadIdx.x;
    if (e >= N_EDGES_SL) return;
    int s, d;
    if (e < N_EDGES) { s = edge[e]; d = edge[N_EDGES + e]; }
    else { s = e - N_EDGES; d = s; }
    int pos = row_ptr[d] + atomicAdd(&cursor[d], 1);
    esrc[pos] = s;
}

// ---------------- fp32 tiled GEMM: C[M,N] = A[M,K] @ B[K,N] ----------------
// requires N % 64 == 0, K % 32 == 0; M arbitrary (row-guarded)
__global__ __launch_bounds__(256) void gemm_f32(const float* __restrict__ A,
                                                const float* __restrict__ B,
                                                float* __restrict__ C,
                                                int M, int N, int K) {
    __shared__ __align__(16) float As[64][33]; // +1 pad: conflict-free column reads
    __shared__ __align__(16) float Bs[32][64];
    int tid = threadIdx.x;
    int tx = tid & 15, ty = tid >> 4;
    int rowBase = blockIdx.y * 64;
    int colBase = blockIdx.x * 64;
    float acc[4][4] = {};
    int ar = tid >> 2;        // 0..63
    int ac = (tid & 3) * 8;   // 0,8,16,24
    int br = tid >> 3;        // 0..31
    int bc = (tid & 7) * 8;   // 0..56
    for (int kk = 0; kk < K; kk += 32) {
        // stage A tile 64x32
        {
            int grow = rowBase + ar;
            float4 v0 = make_float4(0.f, 0.f, 0.f, 0.f), v1 = v0;
            if (grow < M) {
                const float4* src = (const float4*)(A + (size_t)grow * K + kk + ac);
                v0 = src[0];
                v1 = src[1];
            }
            As[ar][ac + 0] = v0.x; As[ar][ac + 1] = v0.y;
            As[ar][ac + 2] = v0.z; As[ar][ac + 3] = v0.w;
            As[ar][ac + 4] = v1.x; As[ar][ac + 5] = v1.y;
            As[ar][ac + 6] = v1.z; As[ar][ac + 7] = v1.w;
        }
        // stage B tile 32x64
        {
            const float4* src = (const float4*)(B + (size_t)(kk + br) * N + colBase + bc);
            float4 v0 = src[0], v1 = src[1];
            *(float4*)&Bs[br][bc] = v0;
            *(float4*)&Bs[br][bc + 4] = v1;
        }
        __syncthreads();
#pragma unroll
        for (int k2 = 0; k2 < 32; ++k2) {
            float a0 = As[ty * 4 + 0][k2];
            float a1 = As[ty * 4 + 1][k2];
            float a2 = As[ty * 4 + 2][k2];
            float a3 = As[ty * 4 + 3][k2];
            float4 b = *(const float4*)&Bs[k2][tx * 4];
            acc[0][0] += a0 * b.x; acc[0][1] += a0 * b.y; acc[0][2] += a0 * b.z; acc[0][3] += a0 * b.w;
            acc[1][0] += a1 * b.x; acc[1][1] += a1 * b.y; acc[1][2] += a1 * b.z; acc[1][3] += a1 * b.w;
            acc[2][0] += a2 * b.x; acc[2][1] += a2 * b.y; acc[2][2] += a2 * b.z; acc[2][3] += a2 * b.w;
            acc[3][0] += a3 * b.x; acc[3][1] += a3 * b.y; acc[3][2] += a3 * b.z; acc[3][3] += a3 * b.w;
        }
        __syncthreads();
    }
#pragma unroll
    for (int i = 0; i < 4; ++i) {
        int grow = rowBase + ty * 4 + i;
        if (grow < M) {
            float4 v = make_float4(acc[i][0], acc[i][1], acc[i][2], acc[i][3]);
            *(float4*)(C + (size_t)grow * N + colBase + tx * 4) = v;
        }
    }
}

// ---------------- attention scores ----------------
// layer 1: one wave per (node, head)
__global__ __launch_bounds__(256) void scores1(const float* __restrict__ h1,
                                               const float* __restrict__ att_src,
                                               const float* __restrict__ att_dst,
                                               float* __restrict__ a_src,
                                               float* __restrict__ a_dst) {
    int wid = (blockIdx.x * 256 + threadIdx.x) >> 6;
    int lane = threadIdx.x & 63;
    if (wid >= N_NODES * HEADS1) return;
    int n = wid / HEADS1;
    int h = wid - n * HEADS1;
    float v = h1[(size_t)n * D1 + h * 64 + lane];
    float vs = v * att_src[h * 64 + lane];
    float vd = v * att_dst[h * 64 + lane];
#pragma unroll
    for (int off = 32; off > 0; off >>= 1) {
        vs += __shfl_xor(vs, off, 64);
        vd += __shfl_xor(vd, off, 64);
    }
    if (lane == 0) { a_src[wid] = vs; a_dst[wid] = vd; }
}

// layer 2: one wave per node (heads=1)
__global__ __launch_bounds__(256) void scores2(const float* __restrict__ h2,
                                               const float* __restrict__ att_src,
                                               const float* __restrict__ att_dst,
                                               float* __restrict__ a_src,
                                               float* __restrict__ a_dst) {
    int wid = (blockIdx.x * 256 + threadIdx.x) >> 6;
    int lane = threadIdx.x & 63;
    if (wid >= N_NODES) return;
    float v = h2[(size_t)wid * 64 + lane];
    float vs = v * att_src[lane];
    float vd = v * att_dst[lane];
#pragma unroll
    for (int off = 32; off > 0; off >>= 1) {
        vs += __shfl_xor(vs, off, 64);
        vd += __shfl_xor(vd, off, 64);
    }
    if (lane == 0) { a_src[wid] = vs; a_dst[wid] = vd; }
}

// ---------------- GAT aggregation, layer 1 (5 heads x 64ch), relu + bias ----------------
__global__ __launch_bounds__(256) void gat_agg1(const int* __restrict__ row_ptr,
                                                const int* __restrict__ esrc,
                                                const float* __restrict__ h1,
                                                const float* __restrict__ a_src,
                                                const float* __restrict__ a_dst,
                                                const float* __restrict__ b1,
                                                float* __restrict__ z1) {
    int wid = (blockIdx.x * 256 + threadIdx.x) >> 6;
    int lane = threadIdx.x & 63;
    if (wid >= N_NODES) return;
    int node = wid;
    int start = row_ptr[node], end = row_ptr[node + 1];
    float adst[HEADS1];
#pragma unroll
    for (int h = 0; h < HEADS1; ++h) adst[h] = a_dst[node * HEADS1 + h];
    // pass 1: per-head max over incoming edges (every node has a self loop -> finite)
    float m[HEADS1];
#pragma unroll
    for (int h = 0; h < HEADS1; ++h) m[h] = -1e30f;
    for (int k = start + lane; k < end; k += 64) {
        int j = esrc[k];
#pragma unroll
        for (int h = 0; h < HEADS1; ++h) {
            float e = leaky(a_src[j * HEADS1 + h] + adst[h]);
            m[h] = fmaxf(m[h], e);
        }
    }
#pragma unroll
    for (int h = 0; h < HEADS1; ++h)
#pragma unroll
        for (int off = 32; off > 0; off >>= 1)
            m[h] = fmaxf(m[h], __shfl_xor(m[h], off, 64));
    // pass 2: denominator
    float s[HEADS1];
#pragma unroll
    for (int h = 0; h < HEADS1; ++h) s[h] = 0.f;
    for (int k = start + lane; k < end; k += 64) {
        int j = esrc[k];
#pragma unroll
        for (int h = 0; h < HEADS1; ++h) {
            float e = leaky(a_src[j * HEADS1 + h] + adst[h]);
            s[h] += __expf(e - m[h]);
        }
    }
#pragma unroll
    for (int h = 0; h < HEADS1; ++h)
#pragma unroll
        for (int off = 32; off > 0; off >>= 1)
            s[h] += __shfl_xor(s[h], off, 64);
    float rinv[HEADS1];
#pragma unroll
    for (int h = 0; h < HEADS1; ++h) rinv[h] = 1.f / (s[h] + 1e-16f);
    // pass 3: weighted accumulate (whole wave walks edges together; lane = channel)
    float acc[HEADS1];
#pragma unroll
    for (int h = 0; h < HEADS1; ++h) acc[h] = 0.f;
    for (int k = start; k < end; ++k) {
        int j = esrc[k];
        const float* hrow = h1 + (size_t)j * D1;
#pragma unroll
        for (int h = 0; h < HEADS1; ++h) {
            float e = leaky(a_src[j * HEADS1 + h] + adst[h]);
            float alpha = __expf(e - m[h]) * rinv[h];
            acc[h] += alpha * hrow[h * 64 + lane];
        }
    }
#pragma unroll
    for (int h = 0; h < HEADS1; ++h) {
        float v = acc[h] + b1[h * 64 + lane];
        z1[(size_t)node * D1 + h * 64 + lane] = fmaxf(v, 0.f); // relu fused
    }
}

// ---------------- GAT aggregation, layer 2 (1 head x 64ch), + bias ----------------
__global__ __launch_bounds__(256) void gat_agg2(const int* __restrict__ row_ptr,
                                                const int* __restrict__ esrc,
                                                const float* __restrict__ h2,
                                                const float* __restrict__ a_src,
                                                const float* __restrict__ a_dst,
                                                const float* __restrict__ b2,
                                                float* __restrict__ z2) {
    int wid = (blockIdx.x * 256 + threadIdx.x) >> 6;
    int lane = threadIdx.x & 63;
    if (wid >= N_NODES) return;
    int node = wid;
    int start = row_ptr[node], end = row_ptr[node + 1];
    float adst = a_dst[node];
    float m = -1e30f;
    for (int k = start + lane; k < end; k += 64)
        m = fmaxf(m, leaky(a_src[esrc[k]] + adst));
#pragma unroll
    for (int off = 32; off > 0; off >>= 1)
        m = fmaxf(m, __shfl_xor(m, off, 64));
    float s = 0.f;
    for (int k = start + lane; k < end; k += 64)
        s += __expf(leaky(a_src[esrc[k]] + adst) - m);
#pragma unroll
    for (int off = 32; off > 0; off >>= 1)
        s += __shfl_xor(s, off, 64);
    float rinv = 1.f / (s + 1e-16f);
    float acc = 0.f;
    for (int k = start; k < end; ++k) {
        int j = esrc[k];
        float alpha = __expf(leaky(a_src[j] + adst) - m) * rinv;
        acc += alpha * h2[(size_t)j * 64 + lane];
    }
    z2[(size_t)node * 64 + lane] = acc + b2[lane];
}

// ---------------- decode: out[k] = dot(z2[a], z2[b]) ----------------
__global__ __launch_bounds__(256) void decode_k(const int* __restrict__ pos,
                                                const int* __restrict__ neg,
                                                const float* __restrict__ z2,
                                                float* __restrict__ out) {
    int wid = (blockIdx.x * 256 + threadIdx.x) >> 6;
    int lane = threadIdx.x & 63;
    if (wid >= 2 * PE_CNT) return;
    int a, b;
    if (wid < PE_CNT) { a = pos[wid]; b = pos[PE_CNT + wid]; }
    else { int k = wid - PE_CNT; a = neg[k]; b = neg[PE_CNT + k]; }
    float v = z2[(size_t)a * 64 + lane] * z2[(size_t)b * 64 + lane];
#pragma unroll
    for (int off = 32; off > 0; off >>= 1)
        v += __shfl_xor(v, off, 64);
    if (lane == 0) out[wid] = v;
}

extern "C" void kernel_launch(void* const* d_in, const int* in_sizes, int n_in,
                              void* d_out, int out_size, void* d_ws, size_t ws_size,
                              hipStream_t stream) {
    const float* x        = (const float*)d_in[0];
    const int* edge_index = (const int*)d_in[1];
    const int* pos_ei     = (const int*)d_in[2];
    const int* neg_ei     = (const int*)d_in[3];
    const float* W1       = (const float*)d_in[4];
    const float* att_src1 = (const float*)d_in[5];
    const float* att_dst1 = (const float*)d_in[6];
    const float* b1       = (const float*)d_in[7];
    const float* W2       = (const float*)d_in[8];
    const float* att_src2 = (const float*)d_in[9];
    const float* att_dst2 = (const float*)d_in[10];
    const float* b2       = (const float*)d_in[11];
    float* out            = (float*)d_out;

    char* ws = (char*)d_ws;
    size_t off = 0;
    auto alloc = [&](size_t bytes) -> void* {
        void* p = ws + off;
        off = (off + bytes + 255) & ~(size_t)255;
        return p;
    };
    float* h1     = (float*)alloc(sizeof(float) * (size_t)N_NODES * D1);
    float* z1     = (float*)alloc(sizeof(float) * (size_t)N_NODES * D1);
    float* h2     = (float*)alloc(sizeof(float) * (size_t)N_NODES * OUT_CH);
    float* z2     = (float*)alloc(sizeof(float) * (size_t)N_NODES * OUT_CH);
    float* a_src1 = (float*)alloc(sizeof(float) * (size_t)N_NODES * HEADS1);
    float* a_dst1 = (float*)alloc(sizeof(float) * (size_t)N_NODES * HEADS1);
    float* a_src2 = (float*)alloc(sizeof(float) * (size_t)N_NODES);
    float* a_dst2 = (float*)alloc(sizeof(float) * (size_t)N_NODES);
    int* cnt      = (int*)alloc(sizeof(int) * (size_t)2 * N_NODES); // cnt + cursor contiguous
    int* cursor   = cnt + N_NODES;
    int* row_ptr  = (int*)alloc(sizeof(int) * (N_NODES + 1));
    int* esrc     = (int*)alloc(sizeof(int) * (size_t)N_EDGES_SL);

    // CSR build (shared by both GAT layers)
    zero_i32<<<(2 * N_NODES + 255) / 256, 256, 0, stream>>>(cnt, 2 * N_NODES);
    count_dst<<<(N_EDGES_SL + 255) / 256, 256, 0, stream>>>(edge_index, cnt);
    scan30000<<<1, 1024, 0, stream>>>(cnt, row_ptr);
    scatter_edges<<<(N_EDGES_SL + 255) / 256, 256, 0, stream>>>(edge_index, row_ptr, cursor, esrc);

    // layer 1
    dim3 g1(D1 / 64, (N_NODES + 63) / 64);
    gemm_f32<<<g1, 256, 0, stream>>>(x, W1, h1, N_NODES, D1, IN_CH);
    scores1<<<(N_NODES * HEADS1) / 4, 256, 0, stream>>>(h1, att_src1, att_dst1, a_src1, a_dst1);
    gat_agg1<<<N_NODES / 4, 256, 0, stream>>>(row_ptr, esrc, h1, a_src1, a_dst1, b1, z1);

    // layer 2
    dim3 g2(OUT_CH / 64, (N_NODES + 63) / 64);
    gemm_f32<<<g2, 256, 0, stream>>>(z1, W2, h2, N_NODES, OUT_CH, D1);
    scores2<<<N_NODES / 4, 256, 0, stream>>>(h2, att_src2, att_dst2, a_src2, a_dst2);
    gat_agg2<<<N_NODES / 4, 256, 0, stream>>>(row_ptr, esrc, h2, a_src2, a_dst2, b2, z2);

    // decode
    decode_k<<<(2 * PE_CNT) / 4, 256, 0, stream>>>(pos_ei, neg_ei, z2, out);

    (void)in_sizes; (void)n_in; (void)out_size; (void)ws_size;
}

// Round 2
// 396.560 us; speedup vs baseline: 1.1858x; 1.1858x over previous
//
#include <hip/hip_runtime.h>
#include <cstdint>
#include <cstddef>

#define N_NODES 30000
#define N_EDGES 480000
#define N_EDGES_SL (N_EDGES + N_NODES) // 510000
#define IN_CH 128
#define HEADS1 5
#define C1 64
#define D1 (HEADS1 * C1) // 320
#define OUT_CH 64
#define PE_CNT 100000
#define NEG_SLOPE 0.2f

static __device__ __forceinline__ float leaky(float x) {
    return x > 0.f ? x : NEG_SLOPE * x;
}

// ---------------- utility ----------------
__global__ void zero_i32(int* __restrict__ p, int n) {
    int i = blockIdx.x * blockDim.x + threadIdx.x;
    if (i < n) p[i] = 0;
}

// ---------------- CSR build (counting sort by dst) ----------------
__global__ void count_dst(const int* __restrict__ edge, int* __restrict__ cnt) {
    int e = blockIdx.x * blockDim.x + threadIdx.x;
    if (e >= N_EDGES_SL) return;
    int d = (e < N_EDGES) ? edge[N_EDGES + e] : (e - N_EDGES);
    atomicAdd(&cnt[d], 1);
}

// single block, 1024 threads, 30 elems/thread, one block-scan (2 barriers)
__global__ __launch_bounds__(1024) void scan_csr(const int* __restrict__ cnt,
                                                 int* __restrict__ row_ptr) {
    const int CH = 30; // 1024*30 = 30720 >= 30000
    int t = threadIdx.x;
    int lane = t & 63, wv = t >> 6; // 16 waves
    int base = t * CH;
    int vals[CH];
    int sum = 0;
#pragma unroll
    for (int i = 0; i < CH; ++i) {
        int idx = base + i;
        int v = (idx < N_NODES) ? cnt[idx] : 0;
        vals[i] = v;
        sum += v;
    }
    // wave-level inclusive scan of per-thread sums
    int inc = sum;
#pragma unroll
    for (int off = 1; off < 64; off <<= 1) {
        int u = __shfl_up(inc, off, 64);
        if (lane >= off) inc += u;
    }
    __shared__ int wsum[16];
    __shared__ int wbase[16];
    if (lane == 63) wsum[wv] = inc;
    __syncthreads();
    if (wv == 0) {
        int v = (lane < 16) ? wsum[lane] : 0;
        int iv = v;
#pragma unroll
        for (int off = 1; off < 64; off <<= 1) {
            int u = __shfl_up(iv, off, 64);
            if (lane >= off) iv += u;
        }
        if (lane < 16) wbase[lane] = iv - v; // exclusive
    }
    __syncthreads();
    int run = wbase[wv] + inc - sum; // exclusive base for this thread
#pragma unroll
    for (int i = 0; i < CH; ++i) {
        int idx = base + i;
        if (idx < N_NODES) row_ptr[idx] = run;
        run += vals[i];
    }
    if (t == 1023) row_ptr[N_NODES] = run; // tail vals are 0 -> run == total
}

__global__ void scatter_edges(const int* __restrict__ edge, const int* __restrict__ row_ptr,
                              int* __restrict__ cursor, int* __restrict__ esrc) {
    int e = blockIdx.x * blockDim.x + threadIdx.x;
    if (e >= N_EDGES_SL) return;
    int s, d;
    if (e < N_EDGES) { s = edge[e]; d = edge[N_EDGES + e]; }
    else { s = e - N_EDGES; d = s; }
    int pos = row_ptr[d] + atomicAdd(&cursor[d], 1);
    esrc[pos] = s;
}

// ---------------- fp32 tiled GEMM + fused attention-score epilogue ----------------
// C[M,N] = A[M,K] @ B[K,N];  N%64==0, K%32==0, M row-guarded.
// If att_src != nullptr: each 64-wide col tile is one head h = blockIdx.x;
// emits as_out[row*heads+h] = dot(C_row_tile, att_src[h]), same for ad_out.
__global__ __launch_bounds__(256) void gemm_f32_att(const float* __restrict__ A,
                                                    const float* __restrict__ B,
                                                    float* __restrict__ C,
                                                    int M, int N, int K,
                                                    const float* __restrict__ att_src,
                                                    const float* __restrict__ att_dst,
                                                    float* __restrict__ as_out,
                                                    float* __restrict__ ad_out,
                                                    int heads) {
    __shared__ __align__(16) float As[64][33]; // +1 pad: conflict-free column reads
    __shared__ __align__(16) float Bs[32][64];
    int tid = threadIdx.x;
    int tx = tid & 15, ty = tid >> 4;
    int rowBase = blockIdx.y * 64;
    int colBase = blockIdx.x * 64;
    float acc[4][4] = {};
    int ar = tid >> 2;        // 0..63
    int ac = (tid & 3) * 8;   // 0,8,16,24
    int br = tid >> 3;        // 0..31
    int bc = (tid & 7) * 8;   // 0..56
    for (int kk = 0; kk < K; kk += 32) {
        {
            int grow = rowBase + ar;
            float4 v0 = make_float4(0.f, 0.f, 0.f, 0.f), v1 = v0;
            if (grow < M) {
                const float4* src = (const float4*)(A + (size_t)grow * K + kk + ac);
                v0 = src[0];
                v1 = src[1];
            }
            As[ar][ac + 0] = v0.x; As[ar][ac + 1] = v0.y;
            As[ar][ac + 2] = v0.z; As[ar][ac + 3] = v0.w;
            As[ar][ac + 4] = v1.x; As[ar][ac + 5] = v1.y;
            As[ar][ac + 6] = v1.z; As[ar][ac + 7] = v1.w;
        }
        {
            const float4* src = (const float4*)(B + (size_t)(kk + br) * N + colBase + bc);
            float4 v0 = src[0], v1 = src[1];
            *(float4*)&Bs[br][bc] = v0;
            *(float4*)&Bs[br][bc + 4] = v1;
        }
        __syncthreads();
#pragma unroll
        for (int k2 = 0; k2 < 32; ++k2) {
            float a0 = As[ty * 4 + 0][k2];
            float a1 = As[ty * 4 + 1][k2];
            float a2 = As[ty * 4 + 2][k2];
            float a3 = As[ty * 4 + 3][k2];
            float4 b = *(const float4*)&Bs[k2][tx * 4];
            acc[0][0] += a0 * b.x; acc[0][1] += a0 * b.y; acc[0][2] += a0 * b.z; acc[0][3] += a0 * b.w;
            acc[1][0] += a1 * b.x; acc[1][1] += a1 * b.y; acc[1][2] += a1 * b.z; acc[1][3] += a1 * b.w;
            acc[2][0] += a2 * b.x; acc[2][1] += a2 * b.y; acc[2][2] += a2 * b.z; acc[2][3] += a2 * b.w;
            acc[3][0] += a3 * b.x; acc[3][1] += a3 * b.y; acc[3][2] += a3 * b.z; acc[3][3] += a3 * b.w;
        }
        __syncthreads();
    }
#pragma unroll
    for (int i = 0; i < 4; ++i) {
        int grow = rowBase + ty * 4 + i;
        if (grow < M) {
            float4 v = make_float4(acc[i][0], acc[i][1], acc[i][2], acc[i][3]);
            *(float4*)(C + (size_t)grow * N + colBase + tx * 4) = v;
        }
    }
    if (att_src) {
        int h = colBase >> 6;
        float s0 = att_src[colBase + tx * 4 + 0], s1 = att_src[colBase + tx * 4 + 1];
        float s2 = att_src[colBase + tx * 4 + 2], s3 = att_src[colBase + tx * 4 + 3];
        float d0 = att_dst[colBase + tx * 4 + 0], d1 = att_dst[colBase + tx * 4 + 1];
        float d2 = att_dst[colBase + tx * 4 + 2], d3 = att_dst[colBase + tx * 4 + 3];
#pragma unroll
        for (int i = 0; i < 4; ++i) {
            float ps = acc[i][0] * s0 + acc[i][1] * s1 + acc[i][2] * s2 + acc[i][3] * s3;
            float pd = acc[i][0] * d0 + acc[i][1] * d1 + acc[i][2] * d2 + acc[i][3] * d3;
            // reduce over the 16 tx lanes (same ty group = 16 contiguous lanes)
#pragma unroll
            for (int off = 1; off < 16; off <<= 1) {
                ps += __shfl_xor(ps, off, 64);
                pd += __shfl_xor(pd, off, 64);
            }
            int grow = rowBase + ty * 4 + i;
            if (tx == 0 && grow < M) {
                as_out[grow * heads + h] = ps;
                ad_out[grow * heads + h] = pd;
            }
        }
    }
}

// ---------------- softmax denom: wave per node, lane = edge ----------------
// writes w[e*H+h] = exp(e_leaky - m) and rinv[node*H+h] = 1/(sum+eps)
__global__ __launch_bounds__(256) void denom1(const int* __restrict__ row_ptr,
                                              const int* __restrict__ esrc,
                                              const float* __restrict__ a_src,
                                              const float* __restrict__ a_dst,
                                              float* __restrict__ w,
                                              float* __restrict__ rinv) {
    int wid = (blockIdx.x * 256 + threadIdx.x) >> 6;
    int lane = threadIdx.x & 63;
    if (wid >= N_NODES) return;
    int start = row_ptr[wid], end = row_ptr[wid + 1];
    float adst[HEADS1];
#pragma unroll
    for (int h = 0; h < HEADS1; ++h) adst[h] = a_dst[wid * HEADS1 + h];
    float m[HEADS1];
#pragma unroll
    for (int h = 0; h < HEADS1; ++h) m[h] = -1e30f;
    for (int k = start + lane; k < end; k += 64) {
        int j = esrc[k];
#pragma unroll
        for (int h = 0; h < HEADS1; ++h)
            m[h] = fmaxf(m[h], leaky(a_src[j * HEADS1 + h] + adst[h]));
    }
#pragma unroll
    for (int h = 0; h < HEADS1; ++h)
#pragma unroll
        for (int off = 32; off > 0; off >>= 1)
            m[h] = fmaxf(m[h], __shfl_xor(m[h], off, 64));
    float s[HEADS1];
#pragma unroll
    for (int h = 0; h < HEADS1; ++h) s[h] = 0.f;
    for (int k = start + lane; k < end; k += 64) {
        int j = esrc[k];
#pragma unroll
        for (int h = 0; h < HEADS1; ++h) {
            float ex = __expf(leaky(a_src[j * HEADS1 + h] + adst[h]) - m[h]);
            s[h] += ex;
            w[(size_t)k * HEADS1 + h] = ex;
        }
    }
#pragma unroll
    for (int h = 0; h < HEADS1; ++h)
#pragma unroll
        for (int off = 32; off > 0; off >>= 1)
            s[h] += __shfl_xor(s[h], off, 64);
    if (lane == 0) {
#pragma unroll
        for (int h = 0; h < HEADS1; ++h)
            rinv[wid * HEADS1 + h] = 1.f / (s[h] + 1e-16f);
    }
}

__global__ __launch_bounds__(256) void denom2(const int* __restrict__ row_ptr,
                                              const int* __restrict__ esrc,
                                              const float* __restrict__ a_src,
                                              const float* __restrict__ a_dst,
                                              float* __restrict__ w,
                                              float* __restrict__ rinv) {
    int wid = (blockIdx.x * 256 + threadIdx.x) >> 6;
    int lane = threadIdx.x & 63;
    if (wid >= N_NODES) return;
    int start = row_ptr[wid], end = row_ptr[wid + 1];
    float adst = a_dst[wid];
    float m = -1e30f;
    for (int k = start + lane; k < end; k += 64)
        m = fmaxf(m, leaky(a_src[esrc[k]] + adst));
#pragma unroll
    for (int off = 32; off > 0; off >>= 1)
        m = fmaxf(m, __shfl_xor(m, off, 64));
    float s = 0.f;
    for (int k = start + lane; k < end; k += 64) {
        float ex = __expf(leaky(a_src[esrc[k]] + adst) - m);
        s += ex;
        w[k] = ex;
    }
#pragma unroll
    for (int off = 32; off > 0; off >>= 1)
        s += __shfl_xor(s, off, 64);
    if (lane == 0) rinv[wid] = 1.f / (s + 1e-16f);
}

// ---------------- weighted accumulate: one wave per (node,head), lane = channel ----------------
__global__ __launch_bounds__(256) void accum1(const int* __restrict__ row_ptr,
                                              const int* __restrict__ esrc,
                                              const float* __restrict__ h1,
                                              const float* __restrict__ w,
                                              const float* __restrict__ rinv,
                                              const float* __restrict__ b1,
                                              float* __restrict__ z1) {
    int wid = (blockIdx.x * 256 + threadIdx.x) >> 6;
    int lane = threadIdx.x & 63;
    if (wid >= N_NODES * HEADS1) return;
    int node = wid / HEADS1;
    int h = wid - node * HEADS1;
    int start = row_ptr[node], end = row_ptr[node + 1];
    float r = rinv[wid];
    float a0 = 0.f, a1 = 0.f, a2 = 0.f, a3 = 0.f;
    const float* hb = h1 + h * 64 + lane;
    int k = start;
    for (; k + 3 < end; k += 4) {
        int j0 = esrc[k], j1 = esrc[k + 1], j2 = esrc[k + 2], j3 = esrc[k + 3];
        float w0 = w[(size_t)k * HEADS1 + h];
        float w1 = w[(size_t)(k + 1) * HEADS1 + h];
        float w2 = w[(size_t)(k + 2) * HEADS1 + h];
        float w3 = w[(size_t)(k + 3) * HEADS1 + h];
        a0 += w0 * hb[(size_t)j0 * D1];
        a1 += w1 * hb[(size_t)j1 * D1];
        a2 += w2 * hb[(size_t)j2 * D1];
        a3 += w3 * hb[(size_t)j3 * D1];
    }
    for (; k < end; ++k)
        a0 += w[(size_t)k * HEADS1 + h] * hb[(size_t)esrc[k] * D1];
    float v = (a0 + a1 + a2 + a3) * r + b1[h * 64 + lane];
    z1[(size_t)node * D1 + h * 64 + lane] = fmaxf(v, 0.f); // relu fused
}

__global__ __launch_bounds__(256) void accum2(const int* __restrict__ row_ptr,
                                              const int* __restrict__ esrc,
                                              const float* __restrict__ h2,
                                              const float* __restrict__ w,
                                              const float* __restrict__ rinv,
                                              const float* __restrict__ b2,
                                              float* __restrict__ z2) {
    int wid = (blockIdx.x * 256 + threadIdx.x) >> 6;
    int lane = threadIdx.x & 63;
    if (wid >= N_NODES) return;
    int start = row_ptr[wid], end = row_ptr[wid + 1];
    float r = rinv[wid];
    float a0 = 0.f, a1 = 0.f, a2 = 0.f, a3 = 0.f;
    const float* hb = h2 + lane;
    int k = start;
    for (; k + 3 < end; k += 4) {
        int j0 = esrc[k], j1 = esrc[k + 1], j2 = esrc[k + 2], j3 = esrc[k + 3];
        float w0 = w[k], w1 = w[k + 1], w2 = w[k + 2], w3 = w[k + 3];
        a0 += w0 * hb[(size_t)j0 * OUT_CH];
        a1 += w1 * hb[(size_t)j1 * OUT_CH];
        a2 += w2 * hb[(size_t)j2 * OUT_CH];
        a3 += w3 * hb[(size_t)j3 * OUT_CH];
    }
    for (; k < end; ++k)
        a0 += w[k] * hb[(size_t)esrc[k] * OUT_CH];
    z2[(size_t)wid * OUT_CH + lane] = (a0 + a1 + a2 + a3) * r + b2[lane];
}

// ---------------- decode: 16 lanes per edge, float4 dot ----------------
__global__ __launch_bounds__(256) void decode4(const int* __restrict__ pos,
                                               const int* __restrict__ neg,
                                               const float* __restrict__ z2,
                                               float* __restrict__ out) {
    int t = blockIdx.x * 256 + threadIdx.x;
    int e = t >> 4;
    int lc = t & 15;
    if (e >= 2 * PE_CNT) return;
    int a, b;
    if (e < PE_CNT) { a = pos[e]; b = pos[PE_CNT + e]; }
    else { int k = e - PE_CNT; a = neg[k]; b = neg[PE_CNT + k]; }
    float4 va = *(const float4*)(z2 + (size_t)a * OUT_CH + lc * 4);
    float4 vb = *(const float4*)(z2 + (size_t)b * OUT_CH + lc * 4);
    float v = va.x * vb.x + va.y * vb.y + va.z * vb.z + va.w * vb.w;
#pragma unroll
    for (int off = 1; off < 16; off <<= 1)
        v += __shfl_xor(v, off, 64);
    if (lc == 0) out[e] = v;
}

extern "C" void kernel_launch(void* const* d_in, const int* in_sizes, int n_in,
                              void* d_out, int out_size, void* d_ws, size_t ws_size,
                              hipStream_t stream) {
    const float* x        = (const float*)d_in[0];
    const int* edge_index = (const int*)d_in[1];
    const int* pos_ei     = (const int*)d_in[2];
    const int* neg_ei     = (const int*)d_in[3];
    const float* W1       = (const float*)d_in[4];
    const float* att_src1 = (const float*)d_in[5];
    const float* att_dst1 = (const float*)d_in[6];
    const float* b1       = (const float*)d_in[7];
    const float* W2       = (const float*)d_in[8];
    const float* att_src2 = (const float*)d_in[9];
    const float* att_dst2 = (const float*)d_in[10];
    const float* b2       = (const float*)d_in[11];
    float* out            = (float*)d_out;

    char* ws = (char*)d_ws;
    size_t off = 0;
    auto alloc = [&](size_t bytes) -> void* {
        void* p = ws + off;
        off = (off + bytes + 255) & ~(size_t)255;
        return p;
    };
    float* h1     = (float*)alloc(sizeof(float) * (size_t)N_NODES * D1);
    float* z1     = (float*)alloc(sizeof(float) * (size_t)N_NODES * D1);
    float* h2     = (float*)alloc(sizeof(float) * (size_t)N_NODES * OUT_CH);
    float* z2     = (float*)alloc(sizeof(float) * (size_t)N_NODES * OUT_CH);
    float* a_src1 = (float*)alloc(sizeof(float) * (size_t)N_NODES * HEADS1);
    float* a_dst1 = (float*)alloc(sizeof(float) * (size_t)N_NODES * HEADS1);
    float* a_src2 = (float*)alloc(sizeof(float) * (size_t)N_NODES);
    float* a_dst2 = (float*)alloc(sizeof(float) * (size_t)N_NODES);
    float* w1     = (float*)alloc(sizeof(float) * (size_t)N_EDGES_SL * HEADS1);
    float* rinv1  = (float*)alloc(sizeof(float) * (size_t)N_NODES * HEADS1);
    float* w2     = (float*)alloc(sizeof(float) * (size_t)N_EDGES_SL);
    float* rinv2  = (float*)alloc(sizeof(float) * (size_t)N_NODES);
    int* cnt      = (int*)alloc(sizeof(int) * (size_t)2 * N_NODES);
    int* cursor   = cnt + N_NODES;
    int* row_ptr  = (int*)alloc(sizeof(int) * (N_NODES + 1));
    int* esrc     = (int*)alloc(sizeof(int) * (size_t)N_EDGES_SL);

    // CSR build (shared by both GAT layers)
    zero_i32<<<(2 * N_NODES + 255) / 256, 256, 0, stream>>>(cnt, 2 * N_NODES);
    count_dst<<<(N_EDGES_SL + 255) / 256, 256, 0, stream>>>(edge_index, cnt);
    scan_csr<<<1, 1024, 0, stream>>>(cnt, row_ptr);
    scatter_edges<<<(N_EDGES_SL + 255) / 256, 256, 0, stream>>>(edge_index, row_ptr, cursor, esrc);

    // layer 1: GEMM + fused scores
    dim3 g1(D1 / 64, (N_NODES + 63) / 64);
    gemm_f32_att<<<g1, 256, 0, stream>>>(x, W1, h1, N_NODES, D1, IN_CH,
                                         att_src1, att_dst1, a_src1, a_dst1, HEADS1);
    denom1<<<(N_NODES + 3) / 4, 256, 0, stream>>>(row_ptr, esrc, a_src1, a_dst1, w1, rinv1);
    accum1<<<(N_NODES * HEADS1 + 3) / 4, 256, 0, stream>>>(row_ptr, esrc, h1, w1, rinv1, b1, z1);

    // layer 2: GEMM + fused scores
    dim3 g2(OUT_CH / 64, (N_NODES + 63) / 64);
    gemm_f32_att<<<g2, 256, 0, stream>>>(z1, W2, h2, N_NODES, OUT_CH, D1,
                                         att_src2, att_dst2, a_src2, a_dst2, 1);
    denom2<<<(N_NODES + 3) / 4, 256, 0, stream>>>(row_ptr, esrc, a_src2, a_dst2, w2, rinv2);
    accum2<<<(N_NODES + 3) / 4, 256, 0, stream>>>(row_ptr, esrc, h2, w2, rinv2, b2, z2);

    // decode
    decode4<<<(2 * PE_CNT * 16 + 255) / 256, 256, 0, stream>>>(pos_ei, neg_ei, z2, out);

    (void)in_sizes; (void)n_in; (void)out_size; (void)ws_size;
}

// Round 3
// 380.380 us; speedup vs baseline: 1.2362x; 1.0425x over previous
//
#include <hip/hip_runtime.h>
#include <hip/hip_fp16.h>
#include <cstdint>
#include <cstddef>

#define N_NODES 30000
#define N_EDGES 480000
#define N_EDGES_SL (N_EDGES + N_NODES) // 510000
#define IN_CH 128
#define HEADS1 5
#define C1 64
#define D1 (HEADS1 * C1) // 320
#define OUT_CH 64
#define PE_CNT 100000
#define NEG_SLOPE 0.2f

static __device__ __forceinline__ float leaky(float x) {
    return x > 0.f ? x : NEG_SLOPE * x;
}

// ---------------- utility ----------------
__global__ void zero_i32(int* __restrict__ p, int n) {
    int i = blockIdx.x * blockDim.x + threadIdx.x;
    if (i < n) p[i] = 0;
}

// ---------------- CSR build (counting sort by dst) ----------------
__global__ void count_dst(const int* __restrict__ edge, int* __restrict__ cnt) {
    int e = blockIdx.x * blockDim.x + threadIdx.x;
    if (e >= N_EDGES_SL) return;
    int d = (e < N_EDGES) ? edge[N_EDGES + e] : (e - N_EDGES);
    atomicAdd(&cnt[d], 1);
}

// single block, 1024 threads, 30 elems/thread, one block-scan (2 barriers)
__global__ __launch_bounds__(1024) void scan_csr(const int* __restrict__ cnt,
                                                 int* __restrict__ row_ptr) {
    const int CH = 30; // 1024*30 = 30720 >= 30000
    int t = threadIdx.x;
    int lane = t & 63, wv = t >> 6; // 16 waves
    int base = t * CH;
    int vals[CH];
    int sum = 0;
#pragma unroll
    for (int i = 0; i < CH; ++i) {
        int idx = base + i;
        int v = (idx < N_NODES) ? cnt[idx] : 0;
        vals[i] = v;
        sum += v;
    }
    int inc = sum;
#pragma unroll
    for (int off = 1; off < 64; off <<= 1) {
        int u = __shfl_up(inc, off, 64);
        if (lane >= off) inc += u;
    }
    __shared__ int wsum[16];
    __shared__ int wbase[16];
    if (lane == 63) wsum[wv] = inc;
    __syncthreads();
    if (wv == 0) {
        int v = (lane < 16) ? wsum[lane] : 0;
        int iv = v;
#pragma unroll
        for (int off = 1; off < 64; off <<= 1) {
            int u = __shfl_up(iv, off, 64);
            if (lane >= off) iv += u;
        }
        if (lane < 16) wbase[lane] = iv - v; // exclusive
    }
    __syncthreads();
    int run = wbase[wv] + inc - sum; // exclusive base for this thread
#pragma unroll
    for (int i = 0; i < CH; ++i) {
        int idx = base + i;
        if (idx < N_NODES) row_ptr[idx] = run;
        run += vals[i];
    }
    if (t == 1023) row_ptr[N_NODES] = run;
}

__global__ void scatter_edges(const int* __restrict__ edge, const int* __restrict__ row_ptr,
                              int* __restrict__ cursor, int* __restrict__ esrc) {
    int e = blockIdx.x * blockDim.x + threadIdx.x;
    if (e >= N_EDGES_SL) return;
    int s, d;
    if (e < N_EDGES) { s = edge[e]; d = edge[N_EDGES + e]; }
    else { s = e - N_EDGES; d = s; }
    int pos = row_ptr[d] + atomicAdd(&cursor[d], 1);
    esrc[pos] = s;
}

// ---------------- fp32 tiled GEMM, fp16 output, fused attention-score epilogue ----------------
// Cf16[M,N] (fp16) = A[M,K] @ B[K,N];  N%64==0, K%32==0, M row-guarded.
// Each 64-wide col tile = one head h = blockIdx.x; emits
// as_out[row*heads+h] = dot(C_row_tile_fp32, att_src[h]) (same for ad_out).
__global__ __launch_bounds__(256) void gemm_f32_att(const float* __restrict__ A,
                                                    const float* __restrict__ B,
                                                    __half* __restrict__ Cf16,
                                                    int M, int N, int K,
                                                    const float* __restrict__ att_src,
                                                    const float* __restrict__ att_dst,
                                                    float* __restrict__ as_out,
                                                    float* __restrict__ ad_out,
                                                    int heads) {
    __shared__ __align__(16) float As[64][33]; // +1 pad: conflict-free column reads
    __shared__ __align__(16) float Bs[32][64];
    int tid = threadIdx.x;
    int tx = tid & 15, ty = tid >> 4;
    int rowBase = blockIdx.y * 64;
    int colBase = blockIdx.x * 64;
    float acc[4][4] = {};
    int ar = tid >> 2;        // 0..63
    int ac = (tid & 3) * 8;   // 0,8,16,24
    int br = tid >> 3;        // 0..31
    int bc = (tid & 7) * 8;   // 0..56
    for (int kk = 0; kk < K; kk += 32) {
        {
            int grow = rowBase + ar;
            float4 v0 = make_float4(0.f, 0.f, 0.f, 0.f), v1 = v0;
            if (grow < M) {
                const float4* src = (const float4*)(A + (size_t)grow * K + kk + ac);
                v0 = src[0];
                v1 = src[1];
            }
            As[ar][ac + 0] = v0.x; As[ar][ac + 1] = v0.y;
            As[ar][ac + 2] = v0.z; As[ar][ac + 3] = v0.w;
            As[ar][ac + 4] = v1.x; As[ar][ac + 5] = v1.y;
            As[ar][ac + 6] = v1.z; As[ar][ac + 7] = v1.w;
        }
        {
            const float4* src = (const float4*)(B + (size_t)(kk + br) * N + colBase + bc);
            float4 v0 = src[0], v1 = src[1];
            *(float4*)&Bs[br][bc] = v0;
            *(float4*)&Bs[br][bc + 4] = v1;
        }
        __syncthreads();
#pragma unroll
        for (int k2 = 0; k2 < 32; ++k2) {
            float a0 = As[ty * 4 + 0][k2];
            float a1 = As[ty * 4 + 1][k2];
            float a2 = As[ty * 4 + 2][k2];
            float a3 = As[ty * 4 + 3][k2];
            float4 b = *(const float4*)&Bs[k2][tx * 4];
            acc[0][0] += a0 * b.x; acc[0][1] += a0 * b.y; acc[0][2] += a0 * b.z; acc[0][3] += a0 * b.w;
            acc[1][0] += a1 * b.x; acc[1][1] += a1 * b.y; acc[1][2] += a1 * b.z; acc[1][3] += a1 * b.w;
            acc[2][0] += a2 * b.x; acc[2][1] += a2 * b.y; acc[2][2] += a2 * b.z; acc[2][3] += a2 * b.w;
            acc[3][0] += a3 * b.x; acc[3][1] += a3 * b.y; acc[3][2] += a3 * b.z; acc[3][3] += a3 * b.w;
        }
        __syncthreads();
    }
#pragma unroll
    for (int i = 0; i < 4; ++i) {
        int grow = rowBase + ty * 4 + i;
        if (grow < M) {
            ushort4 pk;
            pk.x = __half_as_ushort(__float2half(acc[i][0]));
            pk.y = __half_as_ushort(__float2half(acc[i][1]));
            pk.z = __half_as_ushort(__float2half(acc[i][2]));
            pk.w = __half_as_ushort(__float2half(acc[i][3]));
            *(ushort4*)(Cf16 + (size_t)grow * N + colBase + tx * 4) = pk;
        }
    }
    {
        int h = colBase >> 6;
        float s0 = att_src[colBase + tx * 4 + 0], s1 = att_src[colBase + tx * 4 + 1];
        float s2 = att_src[colBase + tx * 4 + 2], s3 = att_src[colBase + tx * 4 + 3];
        float d0 = att_dst[colBase + tx * 4 + 0], d1 = att_dst[colBase + tx * 4 + 1];
        float d2 = att_dst[colBase + tx * 4 + 2], d3 = att_dst[colBase + tx * 4 + 3];
#pragma unroll
        for (int i = 0; i < 4; ++i) {
            float ps = acc[i][0] * s0 + acc[i][1] * s1 + acc[i][2] * s2 + acc[i][3] * s3;
            float pd = acc[i][0] * d0 + acc[i][1] * d1 + acc[i][2] * d2 + acc[i][3] * d3;
#pragma unroll
            for (int off = 1; off < 16; off <<= 1) {
                ps += __shfl_xor(ps, off, 64);
                pd += __shfl_xor(pd, off, 64);
            }
            int grow = rowBase + ty * 4 + i;
            if (tx == 0 && grow < M) {
                as_out[grow * heads + h] = ps;
                ad_out[grow * heads + h] = pd;
            }
        }
    }
}

// ---------------- softmax denom: wave per node, lane = edge ----------------
__global__ __launch_bounds__(256) void denom1(const int* __restrict__ row_ptr,
                                              const int* __restrict__ esrc,
                                              const float* __restrict__ a_src,
                                              const float* __restrict__ a_dst,
                                              float* __restrict__ w,
                                              float* __restrict__ rinv) {
    int wid = (blockIdx.x * 256 + threadIdx.x) >> 6;
    int lane = threadIdx.x & 63;
    if (wid >= N_NODES) return;
    int start = row_ptr[wid], end = row_ptr[wid + 1];
    float adst[HEADS1];
#pragma unroll
    for (int h = 0; h < HEADS1; ++h) adst[h] = a_dst[wid * HEADS1 + h];
    float m[HEADS1];
#pragma unroll
    for (int h = 0; h < HEADS1; ++h) m[h] = -1e30f;
    for (int k = start + lane; k < end; k += 64) {
        int j = esrc[k];
#pragma unroll
        for (int h = 0; h < HEADS1; ++h)
            m[h] = fmaxf(m[h], leaky(a_src[j * HEADS1 + h] + adst[h]));
    }
#pragma unroll
    for (int h = 0; h < HEADS1; ++h)
#pragma unroll
        for (int off = 32; off > 0; off >>= 1)
            m[h] = fmaxf(m[h], __shfl_xor(m[h], off, 64));
    float s[HEADS1];
#pragma unroll
    for (int h = 0; h < HEADS1; ++h) s[h] = 0.f;
    for (int k = start + lane; k < end; k += 64) {
        int j = esrc[k];
#pragma unroll
        for (int h = 0; h < HEADS1; ++h) {
            float ex = __expf(leaky(a_src[j * HEADS1 + h] + adst[h]) - m[h]);
            s[h] += ex;
            w[(size_t)k * HEADS1 + h] = ex;
        }
    }
#pragma unroll
    for (int h = 0; h < HEADS1; ++h)
#pragma unroll
        for (int off = 32; off > 0; off >>= 1)
            s[h] += __shfl_xor(s[h], off, 64);
    if (lane == 0) {
#pragma unroll
        for (int h = 0; h < HEADS1; ++h)
            rinv[wid * HEADS1 + h] = 1.f / (s[h] + 1e-16f);
    }
}

__global__ __launch_bounds__(256) void denom2(const int* __restrict__ row_ptr,
                                              const int* __restrict__ esrc,
                                              const float* __restrict__ a_src,
                                              const float* __restrict__ a_dst,
                                              float* __restrict__ w,
                                              float* __restrict__ rinv) {
    int wid = (blockIdx.x * 256 + threadIdx.x) >> 6;
    int lane = threadIdx.x & 63;
    if (wid >= N_NODES) return;
    int start = row_ptr[wid], end = row_ptr[wid + 1];
    float adst = a_dst[wid];
    float m = -1e30f;
    for (int k = start + lane; k < end; k += 64)
        m = fmaxf(m, leaky(a_src[esrc[k]] + adst));
#pragma unroll
    for (int off = 32; off > 0; off >>= 1)
        m = fmaxf(m, __shfl_xor(m, off, 64));
    float s = 0.f;
    for (int k = start + lane; k < end; k += 64) {
        float ex = __expf(leaky(a_src[esrc[k]] + adst) - m);
        s += ex;
        w[k] = ex;
    }
#pragma unroll
    for (int off = 32; off > 0; off >>= 1)
        s += __shfl_xor(s, off, 64);
    if (lane == 0) rinv[wid] = 1.f / (s + 1e-16f);
}

// ---------------- weighted accumulate: one wave per (node,head), fp16 gather ----------------
__global__ __launch_bounds__(256) void accum1(const int* __restrict__ row_ptr,
                                              const int* __restrict__ esrc,
                                              const __half* __restrict__ h1,
                                              const float* __restrict__ w,
                                              const float* __restrict__ rinv,
                                              const float* __restrict__ b1,
                                              float* __restrict__ z1) {
    int wid = (blockIdx.x * 256 + threadIdx.x) >> 6;
    int lane = threadIdx.x & 63;
    if (wid >= N_NODES * HEADS1) return;
    int node = wid / HEADS1;
    int h = wid - node * HEADS1;
    int start = row_ptr[node], end = row_ptr[node + 1];
    float r = rinv[wid];
    float a0 = 0.f, a1 = 0.f, a2 = 0.f, a3 = 0.f;
    const __half* hb = h1 + h * 64 + lane;
    int k = start;
    for (; k + 3 < end; k += 4) {
        int j0 = esrc[k], j1 = esrc[k + 1], j2 = esrc[k + 2], j3 = esrc[k + 3];
        float w0 = w[(size_t)k * HEADS1 + h];
        float w1 = w[(size_t)(k + 1) * HEADS1 + h];
        float w2 = w[(size_t)(k + 2) * HEADS1 + h];
        float w3 = w[(size_t)(k + 3) * HEADS1 + h];
        a0 += w0 * __half2float(hb[(size_t)j0 * D1]);
        a1 += w1 * __half2float(hb[(size_t)j1 * D1]);
        a2 += w2 * __half2float(hb[(size_t)j2 * D1]);
        a3 += w3 * __half2float(hb[(size_t)j3 * D1]);
    }
    for (; k < end; ++k)
        a0 += w[(size_t)k * HEADS1 + h] * __half2float(hb[(size_t)esrc[k] * D1]);
    float v = (a0 + a1 + a2 + a3) * r + b1[h * 64 + lane];
    z1[(size_t)node * D1 + h * 64 + lane] = fmaxf(v, 0.f); // relu fused
}

// layer 2: fp16 gather, fp16 z2 output (decode-only consumer)
__global__ __launch_bounds__(256) void accum2(const int* __restrict__ row_ptr,
                                              const int* __restrict__ esrc,
                                              const __half* __restrict__ h2,
                                              const float* __restrict__ w,
                                              const float* __restrict__ rinv,
                                              const float* __restrict__ b2,
                                              __half* __restrict__ z2) {
    int wid = (blockIdx.x * 256 + threadIdx.x) >> 6;
    int lane = threadIdx.x & 63;
    if (wid >= N_NODES) return;
    int start = row_ptr[wid], end = row_ptr[wid + 1];
    float r = rinv[wid];
    float a0 = 0.f, a1 = 0.f, a2 = 0.f, a3 = 0.f;
    const __half* hb = h2 + lane;
    int k = start;
    for (; k + 3 < end; k += 4) {
        int j0 = esrc[k], j1 = esrc[k + 1], j2 = esrc[k + 2], j3 = esrc[k + 3];
        float w0 = w[k], w1 = w[k + 1], w2 = w[k + 2], w3 = w[k + 3];
        a0 += w0 * __half2float(hb[(size_t)j0 * OUT_CH]);
        a1 += w1 * __half2float(hb[(size_t)j1 * OUT_CH]);
        a2 += w2 * __half2float(hb[(size_t)j2 * OUT_CH]);
        a3 += w3 * __half2float(hb[(size_t)j3 * OUT_CH]);
    }
    for (; k < end; ++k)
        a0 += w[k] * __half2float(hb[(size_t)esrc[k] * OUT_CH]);
    float v = (a0 + a1 + a2 + a3) * r + b2[lane];
    z2[(size_t)wid * OUT_CH + lane] = __float2half(v);
}

// ---------------- decode: 8 lanes per edge, 16B fp16 loads ----------------
__global__ __launch_bounds__(256) void decode8(const int* __restrict__ pos,
                                               const int* __restrict__ neg,
                                               const __half* __restrict__ z2,
                                               float* __restrict__ out) {
    int t = blockIdx.x * 256 + threadIdx.x;
    int e = t >> 3;
    int lc = t & 7;
    if (e >= 2 * PE_CNT) return;
    int a, b;
    if (e < PE_CNT) { a = pos[e]; b = pos[PE_CNT + e]; }
    else { int k = e - PE_CNT; a = neg[k]; b = neg[PE_CNT + k]; }
    union U { float4 f; __half2 h[4]; } ua, ub;
    ua.f = *(const float4*)(z2 + (size_t)a * OUT_CH + lc * 8);
    ub.f = *(const float4*)(z2 + (size_t)b * OUT_CH + lc * 8);
    float v = 0.f;
#pragma unroll
    for (int i = 0; i < 4; ++i) {
        float2 fa = __half22float2(ua.h[i]);
        float2 fb = __half22float2(ub.h[i]);
        v += fa.x * fb.x + fa.y * fb.y;
    }
#pragma unroll
    for (int off = 1; off < 8; off <<= 1)
        v += __shfl_xor(v, off, 64);
    if (lc == 0) out[e] = v;
}

extern "C" void kernel_launch(void* const* d_in, const int* in_sizes, int n_in,
                              void* d_out, int out_size, void* d_ws, size_t ws_size,
                              hipStream_t stream) {
    const float* x        = (const float*)d_in[0];
    const int* edge_index = (const int*)d_in[1];
    const int* pos_ei     = (const int*)d_in[2];
    const int* neg_ei     = (const int*)d_in[3];
    const float* W1       = (const float*)d_in[4];
    const float* att_src1 = (const float*)d_in[5];
    const float* att_dst1 = (const float*)d_in[6];
    const float* b1       = (const float*)d_in[7];
    const float* W2       = (const float*)d_in[8];
    const float* att_src2 = (const float*)d_in[9];
    const float* att_dst2 = (const float*)d_in[10];
    const float* b2       = (const float*)d_in[11];
    float* out            = (float*)d_out;

    char* ws = (char*)d_ws;
    size_t off = 0;
    auto alloc = [&](size_t bytes) -> void* {
        void* p = ws + off;
        off = (off + bytes + 255) & ~(size_t)255;
        return p;
    };
    __half* h1    = (__half*)alloc(sizeof(__half) * (size_t)N_NODES * D1);
    float* z1     = (float*)alloc(sizeof(float) * (size_t)N_NODES * D1);
    __half* h2    = (__half*)alloc(sizeof(__half) * (size_t)N_NODES * OUT_CH);
    __half* z2    = (__half*)alloc(sizeof(__half) * (size_t)N_NODES * OUT_CH);
    float* a_src1 = (float*)alloc(sizeof(float) * (size_t)N_NODES * HEADS1);
    float* a_dst1 = (float*)alloc(sizeof(float) * (size_t)N_NODES * HEADS1);
    float* a_src2 = (float*)alloc(sizeof(float) * (size_t)N_NODES);
    float* a_dst2 = (float*)alloc(sizeof(float) * (size_t)N_NODES);
    float* w1     = (float*)alloc(sizeof(float) * (size_t)N_EDGES_SL * HEADS1);
    float* rinv1  = (float*)alloc(sizeof(float) * (size_t)N_NODES * HEADS1);
    float* w2     = (float*)alloc(sizeof(float) * (size_t)N_EDGES_SL);
    float* rinv2  = (float*)alloc(sizeof(float) * (size_t)N_NODES);
    int* cnt      = (int*)alloc(sizeof(int) * (size_t)2 * N_NODES);
    int* cursor   = cnt + N_NODES;
    int* row_ptr  = (int*)alloc(sizeof(int) * (N_NODES + 1));
    int* esrc     = (int*)alloc(sizeof(int) * (size_t)N_EDGES_SL);

    // CSR build (shared by both GAT layers)
    zero_i32<<<(2 * N_NODES + 255) / 256, 256, 0, stream>>>(cnt, 2 * N_NODES);
    count_dst<<<(N_EDGES_SL + 255) / 256, 256, 0, stream>>>(edge_index, cnt);
    scan_csr<<<1, 1024, 0, stream>>>(cnt, row_ptr);
    scatter_edges<<<(N_EDGES_SL + 255) / 256, 256, 0, stream>>>(edge_index, row_ptr, cursor, esrc);

    // layer 1: GEMM (fp16 out) + fused scores
    dim3 g1(D1 / 64, (N_NODES + 63) / 64);
    gemm_f32_att<<<g1, 256, 0, stream>>>(x, W1, h1, N_NODES, D1, IN_CH,
                                         att_src1, att_dst1, a_src1, a_dst1, HEADS1);
    denom1<<<(N_NODES + 3) / 4, 256, 0, stream>>>(row_ptr, esrc, a_src1, a_dst1, w1, rinv1);
    accum1<<<(N_NODES * HEADS1 + 3) / 4, 256, 0, stream>>>(row_ptr, esrc, h1, w1, rinv1, b1, z1);

    // layer 2: GEMM (fp16 out) + fused scores
    dim3 g2(OUT_CH / 64, (N_NODES + 63) / 64);
    gemm_f32_att<<<g2, 256, 0, stream>>>(z1, W2, h2, N_NODES, OUT_CH, D1,
                                         att_src2, att_dst2, a_src2, a_dst2, 1);
    denom2<<<(N_NODES + 3) / 4, 256, 0, stream>>>(row_ptr, esrc, a_src2, a_dst2, w2, rinv2);
    accum2<<<(N_NODES + 3) / 4, 256, 0, stream>>>(row_ptr, esrc, h2, w2, rinv2, b2, z2);

    // decode
    decode8<<<(2 * PE_CNT * 8 + 255) / 256, 256, 0, stream>>>(pos_ei, neg_ei, z2, out);

    (void)in_sizes; (void)n_in; (void)out_size; (void)ws_size;
}

// Round 4
// 345.043 us; speedup vs baseline: 1.3628x; 1.1024x over previous
//
#include <hip/hip_runtime.h>
#include <hip/hip_fp16.h>
#include <cstdint>
#include <cstddef>

#define N_NODES 30000
#define N_EDGES 480000
#define N_EDGES_SL (N_EDGES + N_NODES) // 510000
#define IN_CH 128
#define HEADS1 5
#define C1 64
#define D1 (HEADS1 * C1) // 320
#define OUT_CH 64
#define PE_CNT 100000
#define NEG_SLOPE 0.2f

static __device__ __forceinline__ float leaky(float x) {
    return x > 0.f ? x : NEG_SLOPE * x;
}

// ---------------- utility ----------------
__global__ void zero_i32(int* __restrict__ p, int n) {
    int i = blockIdx.x * blockDim.x + threadIdx.x;
    if (i < n) p[i] = 0;
}

// ---------------- CSR build (counting sort by dst) ----------------
__global__ void count_dst(const int* __restrict__ edge, int* __restrict__ cnt) {
    int e = blockIdx.x * blockDim.x + threadIdx.x;
    if (e >= N_EDGES_SL) return;
    int d = (e < N_EDGES) ? edge[N_EDGES + e] : (e - N_EDGES);
    atomicAdd(&cnt[d], 1);
}

// single block, 1024 threads, 30 elems/thread, one block-scan (2 barriers)
__global__ __launch_bounds__(1024) void scan_csr(const int* __restrict__ cnt,
                                                 int* __restrict__ row_ptr) {
    const int CH = 30; // 1024*30 = 30720 >= 30000
    int t = threadIdx.x;
    int lane = t & 63, wv = t >> 6; // 16 waves
    int base = t * CH;
    int vals[CH];
    int sum = 0;
#pragma unroll
    for (int i = 0; i < CH; ++i) {
        int idx = base + i;
        int v = (idx < N_NODES) ? cnt[idx] : 0;
        vals[i] = v;
        sum += v;
    }
    int inc = sum;
#pragma unroll
    for (int off = 1; off < 64; off <<= 1) {
        int u = __shfl_up(inc, off, 64);
        if (lane >= off) inc += u;
    }
    __shared__ int wsum[16];
    __shared__ int wbase[16];
    if (lane == 63) wsum[wv] = inc;
    __syncthreads();
    if (wv == 0) {
        int v = (lane < 16) ? wsum[lane] : 0;
        int iv = v;
#pragma unroll
        for (int off = 1; off < 64; off <<= 1) {
            int u = __shfl_up(iv, off, 64);
            if (lane >= off) iv += u;
        }
        if (lane < 16) wbase[lane] = iv - v; // exclusive
    }
    __syncthreads();
    int run = wbase[wv] + inc - sum; // exclusive base for this thread
#pragma unroll
    for (int i = 0; i < CH; ++i) {
        int idx = base + i;
        if (idx < N_NODES) row_ptr[idx] = run;
        run += vals[i];
    }
    if (t == 1023) row_ptr[N_NODES] = run;
}

__global__ void scatter_edges(const int* __restrict__ edge, const int* __restrict__ row_ptr,
                              int* __restrict__ cursor, int* __restrict__ esrc) {
    int e = blockIdx.x * blockDim.x + threadIdx.x;
    if (e >= N_EDGES_SL) return;
    int s, d;
    if (e < N_EDGES) { s = edge[e]; d = edge[N_EDGES + e]; }
    else { s = e - N_EDGES; d = s; }
    int pos = row_ptr[d] + atomicAdd(&cursor[d], 1);
    esrc[pos] = s;
}

// ---------------- fp32 tiled GEMM, fp16 output, fused attention-score epilogue ----------------
__global__ __launch_bounds__(256) void gemm_f32_att(const float* __restrict__ A,
                                                    const float* __restrict__ B,
                                                    __half* __restrict__ Cf16,
                                                    int M, int N, int K,
                                                    const float* __restrict__ att_src,
                                                    const float* __restrict__ att_dst,
                                                    float* __restrict__ as_out,
                                                    float* __restrict__ ad_out,
                                                    int heads) {
    __shared__ __align__(16) float As[64][33]; // +1 pad: conflict-free column reads
    __shared__ __align__(16) float Bs[32][64];
    int tid = threadIdx.x;
    int tx = tid & 15, ty = tid >> 4;
    int rowBase = blockIdx.y * 64;
    int colBase = blockIdx.x * 64;
    float acc[4][4] = {};
    int ar = tid >> 2;        // 0..63
    int ac = (tid & 3) * 8;   // 0,8,16,24
    int br = tid >> 3;        // 0..31
    int bc = (tid & 7) * 8;   // 0..56
    for (int kk = 0; kk < K; kk += 32) {
        {
            int grow = rowBase + ar;
            float4 v0 = make_float4(0.f, 0.f, 0.f, 0.f), v1 = v0;
            if (grow < M) {
                const float4* src = (const float4*)(A + (size_t)grow * K + kk + ac);
                v0 = src[0];
                v1 = src[1];
            }
            As[ar][ac + 0] = v0.x; As[ar][ac + 1] = v0.y;
            As[ar][ac + 2] = v0.z; As[ar][ac + 3] = v0.w;
            As[ar][ac + 4] = v1.x; As[ar][ac + 5] = v1.y;
            As[ar][ac + 6] = v1.z; As[ar][ac + 7] = v1.w;
        }
        {
            const float4* src = (const float4*)(B + (size_t)(kk + br) * N + colBase + bc);
            float4 v0 = src[0], v1 = src[1];
            *(float4*)&Bs[br][bc] = v0;
            *(float4*)&Bs[br][bc + 4] = v1;
        }
        __syncthreads();
#pragma unroll
        for (int k2 = 0; k2 < 32; ++k2) {
            float a0 = As[ty * 4 + 0][k2];
            float a1 = As[ty * 4 + 1][k2];
            float a2 = As[ty * 4 + 2][k2];
            float a3 = As[ty * 4 + 3][k2];
            float4 b = *(const float4*)&Bs[k2][tx * 4];
            acc[0][0] += a0 * b.x; acc[0][1] += a0 * b.y; acc[0][2] += a0 * b.z; acc[0][3] += a0 * b.w;
            acc[1][0] += a1 * b.x; acc[1][1] += a1 * b.y; acc[1][2] += a1 * b.z; acc[1][3] += a1 * b.w;
            acc[2][0] += a2 * b.x; acc[2][1] += a2 * b.y; acc[2][2] += a2 * b.z; acc[2][3] += a2 * b.w;
            acc[3][0] += a3 * b.x; acc[3][1] += a3 * b.y; acc[3][2] += a3 * b.z; acc[3][3] += a3 * b.w;
        }
        __syncthreads();
    }
#pragma unroll
    for (int i = 0; i < 4; ++i) {
        int grow = rowBase + ty * 4 + i;
        if (grow < M) {
            ushort4 pk;
            pk.x = __half_as_ushort(__float2half(acc[i][0]));
            pk.y = __half_as_ushort(__float2half(acc[i][1]));
            pk.z = __half_as_ushort(__float2half(acc[i][2]));
            pk.w = __half_as_ushort(__float2half(acc[i][3]));
            *(ushort4*)(Cf16 + (size_t)grow * N + colBase + tx * 4) = pk;
        }
    }
    {
        int h = colBase >> 6;
        float s0 = att_src[colBase + tx * 4 + 0], s1 = att_src[colBase + tx * 4 + 1];
        float s2 = att_src[colBase + tx * 4 + 2], s3 = att_src[colBase + tx * 4 + 3];
        float d0 = att_dst[colBase + tx * 4 + 0], d1 = att_dst[colBase + tx * 4 + 1];
        float d2 = att_dst[colBase + tx * 4 + 2], d3 = att_dst[colBase + tx * 4 + 3];
#pragma unroll
        for (int i = 0; i < 4; ++i) {
            float ps = acc[i][0] * s0 + acc[i][1] * s1 + acc[i][2] * s2 + acc[i][3] * s3;
            float pd = acc[i][0] * d0 + acc[i][1] * d1 + acc[i][2] * d2 + acc[i][3] * d3;
#pragma unroll
            for (int off = 1; off < 16; off <<= 1) {
                ps += __shfl_xor(ps, off, 64);
                pd += __shfl_xor(pd, off, 64);
            }
            int grow = rowBase + ty * 4 + i;
            if (tx == 0 && grow < M) {
                as_out[grow * heads + h] = ps;
                ad_out[grow * heads + h] = pd;
            }
        }
    }
}

// ---------------- softmax denom: wave per node, lane = edge ----------------
// writes w[h*E + k] (HEAD-MAJOR) and rinv[h*N + node] (HEAD-MAJOR)
__global__ __launch_bounds__(256) void denom1(const int* __restrict__ row_ptr,
                                              const int* __restrict__ esrc,
                                              const float* __restrict__ a_src,
                                              const float* __restrict__ a_dst,
                                              float* __restrict__ w,
                                              float* __restrict__ rinv) {
    int wid = (blockIdx.x * 256 + threadIdx.x) >> 6;
    int lane = threadIdx.x & 63;
    if (wid >= N_NODES) return;
    int start = row_ptr[wid], end = row_ptr[wid + 1];
    float adst[HEADS1];
#pragma unroll
    for (int h = 0; h < HEADS1; ++h) adst[h] = a_dst[wid * HEADS1 + h];
    float m[HEADS1];
#pragma unroll
    for (int h = 0; h < HEADS1; ++h) m[h] = -1e30f;
    for (int k = start + lane; k < end; k += 64) {
        int j = esrc[k];
#pragma unroll
        for (int h = 0; h < HEADS1; ++h)
            m[h] = fmaxf(m[h], leaky(a_src[j * HEADS1 + h] + adst[h]));
    }
#pragma unroll
    for (int h = 0; h < HEADS1; ++h)
#pragma unroll
        for (int off = 32; off > 0; off >>= 1)
            m[h] = fmaxf(m[h], __shfl_xor(m[h], off, 64));
    float s[HEADS1];
#pragma unroll
    for (int h = 0; h < HEADS1; ++h) s[h] = 0.f;
    for (int k = start + lane; k < end; k += 64) {
        int j = esrc[k];
#pragma unroll
        for (int h = 0; h < HEADS1; ++h) {
            float ex = __expf(leaky(a_src[j * HEADS1 + h] + adst[h]) - m[h]);
            s[h] += ex;
            w[(size_t)h * N_EDGES_SL + k] = ex;
        }
    }
#pragma unroll
    for (int h = 0; h < HEADS1; ++h)
#pragma unroll
        for (int off = 32; off > 0; off >>= 1)
            s[h] += __shfl_xor(s[h], off, 64);
    if (lane == 0) {
#pragma unroll
        for (int h = 0; h < HEADS1; ++h)
            rinv[(size_t)h * N_NODES + wid] = 1.f / (s[h] + 1e-16f);
    }
}

__global__ __launch_bounds__(256) void denom2(const int* __restrict__ row_ptr,
                                              const int* __restrict__ esrc,
                                              const float* __restrict__ a_src,
                                              const float* __restrict__ a_dst,
                                              float* __restrict__ w,
                                              float* __restrict__ rinv) {
    int wid = (blockIdx.x * 256 + threadIdx.x) >> 6;
    int lane = threadIdx.x & 63;
    if (wid >= N_NODES) return;
    int start = row_ptr[wid], end = row_ptr[wid + 1];
    float adst = a_dst[wid];
    float m = -1e30f;
    for (int k = start + lane; k < end; k += 64)
        m = fmaxf(m, leaky(a_src[esrc[k]] + adst));
#pragma unroll
    for (int off = 32; off > 0; off >>= 1)
        m = fmaxf(m, __shfl_xor(m, off, 64));
    float s = 0.f;
    for (int k = start + lane; k < end; k += 64) {
        float ex = __expf(leaky(a_src[esrc[k]] + adst) - m);
        s += ex;
        w[k] = ex;
    }
#pragma unroll
    for (int off = 32; off > 0; off >>= 1)
        s += __shfl_xor(s, off, 64);
    if (lane == 0) rinv[wid] = 1.f / (s + 1e-16f);
}

// ---------------- weighted accumulate, layer 1 ----------------
// wave per (node,head), HEAD-MAJOR grid. lane = es*8+cg: 8 edge-sublanes x
// 8 channel-groups; each lane loads 16B (8 fp16 ch) -> wave gathers 8 edges
// (1 KB) per instruction, 2 KB in flight.
__global__ __launch_bounds__(256) void accum1(const int* __restrict__ row_ptr,
                                              const int* __restrict__ esrc,
                                              const __half* __restrict__ h1,
                                              const float* __restrict__ w,    // [h][E]
                                              const float* __restrict__ rinv, // [h][N]
                                              const float* __restrict__ b1,
                                              float* __restrict__ z1) {
    int wid = (blockIdx.x * 256 + threadIdx.x) >> 6;
    int lane = threadIdx.x & 63;
    if (wid >= N_NODES * HEADS1) return;
    int h = wid / N_NODES;        // head-major: per-phase gather footprint ~3.8MB
    int node = wid - h * N_NODES;
    int start = row_ptr[node], end = row_ptr[node + 1];
    int es = lane >> 3;  // 0..7
    int cg = lane & 7;   // 0..7
    const float* wh = w + (size_t)h * N_EDGES_SL;
    const __half* hbase = h1 + h * 64 + cg * 8;
    float acc[8] = {};
    int k = start;
    for (; k + 16 <= end; k += 16) {
        int ka = k + es, kb = k + 8 + es;
        int ja = esrc[ka], jb = esrc[kb];
        float wa = wh[ka], wb = wh[kb];
        float4 va = *(const float4*)(hbase + (size_t)ja * D1);
        float4 vb = *(const float4*)(hbase + (size_t)jb * D1);
        const __half2* pa = (const __half2*)&va;
        const __half2* pb = (const __half2*)&vb;
#pragma unroll
        for (int i = 0; i < 4; ++i) {
            float2 fa = __half22float2(pa[i]);
            float2 fb = __half22float2(pb[i]);
            acc[2 * i]     += wa * fa.x + wb * fb.x;
            acc[2 * i + 1] += wa * fa.y + wb * fb.y;
        }
    }
    for (; k < end; k += 8) {
        int kk = k + es;
        bool ok = kk < end;
        int j = esrc[ok ? kk : end - 1];
        float wgt = ok ? wh[kk] : 0.f;
        float4 v = *(const float4*)(hbase + (size_t)j * D1);
        const __half2* pv = (const __half2*)&v;
#pragma unroll
        for (int i = 0; i < 4; ++i) {
            float2 f = __half22float2(pv[i]);
            acc[2 * i]     += wgt * f.x;
            acc[2 * i + 1] += wgt * f.y;
        }
    }
#pragma unroll
    for (int off = 8; off < 64; off <<= 1)
#pragma unroll
        for (int i = 0; i < 8; ++i)
            acc[i] += __shfl_xor(acc[i], off, 64);
    if (es == 0) {
        float r = rinv[(size_t)h * N_NODES + node];
        const float* bb = b1 + h * 64 + cg * 8;
        float4 o0, o1;
        o0.x = fmaxf(acc[0] * r + bb[0], 0.f);
        o0.y = fmaxf(acc[1] * r + bb[1], 0.f);
        o0.z = fmaxf(acc[2] * r + bb[2], 0.f);
        o0.w = fmaxf(acc[3] * r + bb[3], 0.f);
        o1.x = fmaxf(acc[4] * r + bb[4], 0.f);
        o1.y = fmaxf(acc[5] * r + bb[5], 0.f);
        o1.z = fmaxf(acc[6] * r + bb[6], 0.f);
        o1.w = fmaxf(acc[7] * r + bb[7], 0.f);
        float* dst = z1 + (size_t)node * D1 + h * 64 + cg * 8;
        *(float4*)dst = o0;
        *(float4*)(dst + 4) = o1;
    }
}

// ---------------- weighted accumulate, layer 2 (fp16 out for decode) ----------------
__global__ __launch_bounds__(256) void accum2(const int* __restrict__ row_ptr,
                                              const int* __restrict__ esrc,
                                              const __half* __restrict__ h2,
                                              const float* __restrict__ w,
                                              const float* __restrict__ rinv,
                                              const float* __restrict__ b2,
                                              __half* __restrict__ z2) {
    int wid = (blockIdx.x * 256 + threadIdx.x) >> 6;
    int lane = threadIdx.x & 63;
    if (wid >= N_NODES) return;
    int start = row_ptr[wid], end = row_ptr[wid + 1];
    int es = lane >> 3;
    int cg = lane & 7;
    const __half* hbase = h2 + cg * 8;
    float acc[8] = {};
    int k = start;
    for (; k + 16 <= end; k += 16) {
        int ka = k + es, kb = k + 8 + es;
        int ja = esrc[ka], jb = esrc[kb];
        float wa = w[ka], wb = w[kb];
        float4 va = *(const float4*)(hbase + (size_t)ja * OUT_CH);
        float4 vb = *(const float4*)(hbase + (size_t)jb * OUT_CH);
        const __half2* pa = (const __half2*)&va;
        const __half2* pb = (const __half2*)&vb;
#pragma unroll
        for (int i = 0; i < 4; ++i) {
            float2 fa = __half22float2(pa[i]);
            float2 fb = __half22float2(pb[i]);
            acc[2 * i]     += wa * fa.x + wb * fb.x;
            acc[2 * i + 1] += wa * fa.y + wb * fb.y;
        }
    }
    for (; k < end; k += 8) {
        int kk = k + es;
        bool ok = kk < end;
        int j = esrc[ok ? kk : end - 1];
        float wgt = ok ? w[kk] : 0.f;
        float4 v = *(const float4*)(hbase + (size_t)j * OUT_CH);
        const __half2* pv = (const __half2*)&v;
#pragma unroll
        for (int i = 0; i < 4; ++i) {
            float2 f = __half22float2(pv[i]);
            acc[2 * i]     += wgt * f.x;
            acc[2 * i + 1] += wgt * f.y;
        }
    }
#pragma unroll
    for (int off = 8; off < 64; off <<= 1)
#pragma unroll
        for (int i = 0; i < 8; ++i)
            acc[i] += __shfl_xor(acc[i], off, 64);
    if (es == 0) {
        float r = rinv[wid];
        const float* bb = b2 + cg * 8;
        union { float4 f; __half2 h[4]; } pk;
#pragma unroll
        for (int i = 0; i < 4; ++i) {
            float lo = acc[2 * i] * r + bb[2 * i];
            float hi = acc[2 * i + 1] * r + bb[2 * i + 1];
            pk.h[i] = __floats2half2_rn(lo, hi);
        }
        *(float4*)(z2 + (size_t)wid * OUT_CH + cg * 8) = pk.f;
    }
}

// ---------------- decode: 8 lanes per edge, 16B fp16 loads ----------------
__global__ __launch_bounds__(256) void decode8(const int* __restrict__ pos,
                                               const int* __restrict__ neg,
                                               const __half* __restrict__ z2,
                                               float* __restrict__ out) {
    int t = blockIdx.x * 256 + threadIdx.x;
    int e = t >> 3;
    int lc = t & 7;
    if (e >= 2 * PE_CNT) return;
    int a, b;
    if (e < PE_CNT) { a = pos[e]; b = pos[PE_CNT + e]; }
    else { int k = e - PE_CNT; a = neg[k]; b = neg[PE_CNT + k]; }
    union U { float4 f; __half2 h[4]; } ua, ub;
    ua.f = *(const float4*)(z2 + (size_t)a * OUT_CH + lc * 8);
    ub.f = *(const float4*)(z2 + (size_t)b * OUT_CH + lc * 8);
    float v = 0.f;
#pragma unroll
    for (int i = 0; i < 4; ++i) {
        float2 fa = __half22float2(ua.h[i]);
        float2 fb = __half22float2(ub.h[i]);
        v += fa.x * fb.x + fa.y * fb.y;
    }
#pragma unroll
    for (int off = 1; off < 8; off <<= 1)
        v += __shfl_xor(v, off, 64);
    if (lc == 0) out[e] = v;
}

extern "C" void kernel_launch(void* const* d_in, const int* in_sizes, int n_in,
                              void* d_out, int out_size, void* d_ws, size_t ws_size,
                              hipStream_t stream) {
    const float* x        = (const float*)d_in[0];
    const int* edge_index = (const int*)d_in[1];
    const int* pos_ei     = (const int*)d_in[2];
    const int* neg_ei     = (const int*)d_in[3];
    const float* W1       = (const float*)d_in[4];
    const float* att_src1 = (const float*)d_in[5];
    const float* att_dst1 = (const float*)d_in[6];
    const float* b1       = (const float*)d_in[7];
    const float* W2       = (const float*)d_in[8];
    const float* att_src2 = (const float*)d_in[9];
    const float* att_dst2 = (const float*)d_in[10];
    const float* b2       = (const float*)d_in[11];
    float* out            = (float*)d_out;

    char* ws = (char*)d_ws;
    size_t off = 0;
    auto alloc = [&](size_t bytes) -> void* {
        void* p = ws + off;
        off = (off + bytes + 255) & ~(size_t)255;
        return p;
    };
    __half* h1    = (__half*)alloc(sizeof(__half) * (size_t)N_NODES * D1);
    float* z1     = (float*)alloc(sizeof(float) * (size_t)N_NODES * D1);
    __half* h2    = (__half*)alloc(sizeof(__half) * (size_t)N_NODES * OUT_CH);
    __half* z2    = (__half*)alloc(sizeof(__half) * (size_t)N_NODES * OUT_CH);
    float* a_src1 = (float*)alloc(sizeof(float) * (size_t)N_NODES * HEADS1);
    float* a_dst1 = (float*)alloc(sizeof(float) * (size_t)N_NODES * HEADS1);
    float* a_src2 = (float*)alloc(sizeof(float) * (size_t)N_NODES);
    float* a_dst2 = (float*)alloc(sizeof(float) * (size_t)N_NODES);
    float* w1     = (float*)alloc(sizeof(float) * (size_t)N_EDGES_SL * HEADS1); // [h][E]
    float* rinv1  = (float*)alloc(sizeof(float) * (size_t)N_NODES * HEADS1);    // [h][N]
    float* w2     = (float*)alloc(sizeof(float) * (size_t)N_EDGES_SL);
    float* rinv2  = (float*)alloc(sizeof(float) * (size_t)N_NODES);
    int* cnt      = (int*)alloc(sizeof(int) * (size_t)2 * N_NODES);
    int* cursor   = cnt + N_NODES;
    int* row_ptr  = (int*)alloc(sizeof(int) * (N_NODES + 1));
    int* esrc     = (int*)alloc(sizeof(int) * (size_t)N_EDGES_SL);

    // CSR build (shared by both GAT layers)
    zero_i32<<<(2 * N_NODES + 255) / 256, 256, 0, stream>>>(cnt, 2 * N_NODES);
    count_dst<<<(N_EDGES_SL + 255) / 256, 256, 0, stream>>>(edge_index, cnt);
    scan_csr<<<1, 1024, 0, stream>>>(cnt, row_ptr);
    scatter_edges<<<(N_EDGES_SL + 255) / 256, 256, 0, stream>>>(edge_index, row_ptr, cursor, esrc);

    // layer 1: GEMM (fp16 out) + fused scores
    dim3 g1(D1 / 64, (N_NODES + 63) / 64);
    gemm_f32_att<<<g1, 256, 0, stream>>>(x, W1, h1, N_NODES, D1, IN_CH,
                                         att_src1, att_dst1, a_src1, a_dst1, HEADS1);
    denom1<<<(N_NODES + 3) / 4, 256, 0, stream>>>(row_ptr, esrc, a_src1, a_dst1, w1, rinv1);
    accum1<<<(N_NODES * HEADS1 + 3) / 4, 256, 0, stream>>>(row_ptr, esrc, h1, w1, rinv1, b1, z1);

    // layer 2: GEMM (fp16 out) + fused scores
    dim3 g2(OUT_CH / 64, (N_NODES + 63) / 64);
    gemm_f32_att<<<g2, 256, 0, stream>>>(z1, W2, h2, N_NODES, OUT_CH, D1,
                                         att_src2, att_dst2, a_src2, a_dst2, 1);
    denom2<<<(N_NODES + 3) / 4, 256, 0, stream>>>(row_ptr, esrc, a_src2, a_dst2, w2, rinv2);
    accum2<<<(N_NODES + 3) / 4, 256, 0, stream>>>(row_ptr, esrc, h2, w2, rinv2, b2, z2);

    // decode
    decode8<<<(2 * PE_CNT * 8 + 255) / 256, 256, 0, stream>>>(pos_ei, neg_ei, z2, out);

    (void)in_sizes; (void)n_in; (void)out_size; (void)ws_size;
}

// Round 5
// 311.298 us; speedup vs baseline: 1.5106x; 1.1084x over previous
//
#include <hip/hip_runtime.h>
#include <hip/hip_fp16.h>
#include <cstdint>
#include <cstddef>
#include <type_traits>

#define N_NODES 30000
#define N_EDGES 480000
#define N_EDGES_SL (N_EDGES + N_NODES) // 510000
#define IN_CH 128
#define HEADS1 5
#define C1 64
#define D1 (HEADS1 * C1) // 320
#define OUT_CH 64
#define PE_CNT 100000
#define NEG_SLOPE 0.2f

typedef _Float16 f16x8 __attribute__((ext_vector_type(8)));
typedef float fx4 __attribute__((ext_vector_type(4)));

static __device__ __forceinline__ float leaky(float x) {
    return x > 0.f ? x : NEG_SLOPE * x;
}

// ---------------- utility ----------------
__global__ void zero_i32(int* __restrict__ p, int n) {
    int i = blockIdx.x * blockDim.x + threadIdx.x;
    if (i < n) p[i] = 0;
}

// ---------------- CSR build (counting sort by dst) ----------------
__global__ void count_dst(const int* __restrict__ edge, int* __restrict__ cnt) {
    int e = blockIdx.x * blockDim.x + threadIdx.x;
    if (e >= N_EDGES_SL) return;
    int d = (e < N_EDGES) ? edge[N_EDGES + e] : (e - N_EDGES);
    atomicAdd(&cnt[d], 1);
}

// single block, 1024 threads, 30 coalesced chunk-scans with running carry
__global__ __launch_bounds__(1024) void scan_csr(const int* __restrict__ cnt,
                                                 int* __restrict__ row_ptr) {
    __shared__ int wsum[16];
    __shared__ int wexc[16];
    __shared__ int chtot;
    int t = threadIdx.x, lane = t & 63, wv = t >> 6;
    int carry = 0;
    for (int base = 0; base < N_NODES; base += 1024) {
        int i = base + t;
        int v = (i < N_NODES) ? cnt[i] : 0;
        int inc = v;
#pragma unroll
        for (int off = 1; off < 64; off <<= 1) {
            int u = __shfl_up(inc, off, 64);
            if (lane >= off) inc += u;
        }
        if (lane == 63) wsum[wv] = inc;
        __syncthreads();
        if (wv == 0) {
            int val = (lane < 16) ? wsum[lane] : 0;
            int iv = val;
#pragma unroll
            for (int off = 1; off < 16; off <<= 1) {
                int u = __shfl_up(iv, off, 64);
                if (lane >= off) iv += u;
            }
            if (lane < 16) wexc[lane] = iv - val;
            if (lane == 15) chtot = iv;
        }
        __syncthreads();
        if (i < N_NODES) row_ptr[i] = carry + wexc[wv] + inc - v;
        carry += chtot;
        // next-iter writes to wsum happen after its own first barrier -> safe
    }
    if (t == 0) row_ptr[N_NODES] = carry;
}

__global__ void scatter_edges(const int* __restrict__ edge, const int* __restrict__ row_ptr,
                              int* __restrict__ cursor, int* __restrict__ esrc) {
    int e = blockIdx.x * blockDim.x + threadIdx.x;
    if (e >= N_EDGES_SL) return;
    int s, d;
    if (e < N_EDGES) { s = edge[e]; d = edge[N_EDGES + e]; }
    else { s = e - N_EDGES; d = s; }
    int pos = row_ptr[d] + atomicAdd(&cursor[d], 1);
    esrc[pos] = s;
}

// ---------------- weight prep: W[K][N] fp32 -> Wt[N][K] fp16 ----------------
__global__ void prep_wt(const float* __restrict__ W, __half* __restrict__ Wt, int K, int N) {
    int idx = blockIdx.x * blockDim.x + threadIdx.x;
    if (idx >= K * N) return;
    int k = idx / N, n = idx - k * N;
    Wt[(size_t)n * K + k] = __float2half(W[idx]);
}

// ---------------- MFMA fp16 GEMM + fused attention-score epilogue ----------------
// C[M, NH*64] (fp16) = A[M,K] @ W, with W given as Wt[N][K] fp16 (pre-transposed).
// Block: 256 thr = 4 waves; block tile 64 rows x all N cols (A read once).
// Wave w: rows [w*16, w*16+16). MFMA 16x16x32_f16 fragment layouts (HW-verified):
//   A: lane holds A[m=lane&15][k=quad*8+j]  (quad=lane>>4, j=0..7)
//   B: lane holds B[k=quad*8+j][n=lane&15]  -> contiguous 8 halves of Wt[n][k..]
//   D: lane reg holds D[row=quad*4+reg][col=lane&15]
// Epilogue: as_out[row*NH+h] = dot(Crow_head_h, att_src_h) (fp32 accum), same ad_out.
template<int NH, typename AT>
__global__ __launch_bounds__(256) void gemm_mfma_att(const AT* __restrict__ A,
                                                     const __half* __restrict__ Wt,
                                                     __half* __restrict__ C,
                                                     int M, int K,
                                                     const float* __restrict__ att_src,
                                                     const float* __restrict__ att_dst,
                                                     float* __restrict__ as_out,
                                                     float* __restrict__ ad_out) {
    const int N = NH * 64;
    __shared__ __align__(16) __half As[64][40]; // 32 k + 8 pad halves
    int tid = threadIdx.x;
    int wv = tid >> 6, lane = tid & 63;
    int q = lane >> 4, l16 = lane & 15;
    int rowBase = blockIdx.x * 64;

    fx4 zero4 = {0.f, 0.f, 0.f, 0.f};
    fx4 acc[NH][4];
#pragma unroll
    for (int h = 0; h < NH; ++h)
#pragma unroll
        for (int c = 0; c < 4; ++c) acc[h][c] = zero4;

    int ar = tid >> 2;       // staging row 0..63
    int ak = (tid & 3) * 8;  // staging k offset 0,8,16,24

    for (int kk = 0; kk < K; kk += 32) {
        // stage A tile 64x32 as fp16
        {
            int grow = rowBase + ar;
            if constexpr (std::is_same<AT, float>::value) {
                float4 v0 = make_float4(0.f, 0.f, 0.f, 0.f), v1 = v0;
                if (grow < M) {
                    const float4* s = (const float4*)(A + (size_t)grow * K + kk + ak);
                    v0 = s[0]; v1 = s[1];
                }
                f16x8 hv;
                hv[0] = (_Float16)v0.x; hv[1] = (_Float16)v0.y;
                hv[2] = (_Float16)v0.z; hv[3] = (_Float16)v0.w;
                hv[4] = (_Float16)v1.x; hv[5] = (_Float16)v1.y;
                hv[6] = (_Float16)v1.z; hv[7] = (_Float16)v1.w;
                *(f16x8*)(&As[ar][ak]) = hv;
            } else {
                float4 v = make_float4(0.f, 0.f, 0.f, 0.f);
                if (grow < M)
                    v = *(const float4*)((const __half*)A + (size_t)grow * K + kk + ak);
                *(float4*)(&As[ar][ak]) = v;
            }
        }
        __syncthreads();
        f16x8 af = *(const f16x8*)(&As[wv * 16 + l16][q * 8]);
#pragma unroll
        for (int h = 0; h < NH; ++h) {
#pragma unroll
            for (int c = 0; c < 4; ++c) {
                int col = h * 64 + c * 16 + l16;
                f16x8 bf = *(const f16x8*)(Wt + (size_t)col * K + kk + q * 8);
                acc[h][c] = __builtin_amdgcn_mfma_f32_16x16x32_f16(af, bf, acc[h][c], 0, 0, 0);
            }
        }
        __syncthreads();
    }
    // store C (fp16) + attention epilogue
#pragma unroll
    for (int h = 0; h < NH; ++h) {
        float ps[4] = {0.f, 0.f, 0.f, 0.f};
        float pd[4] = {0.f, 0.f, 0.f, 0.f};
#pragma unroll
        for (int c = 0; c < 4; ++c) {
            int gcol = h * 64 + c * 16 + l16;
            float av = att_src[gcol];
            float dv = att_dst[gcol];
#pragma unroll
            for (int reg = 0; reg < 4; ++reg) {
                int grow = rowBase + wv * 16 + q * 4 + reg;
                float val = acc[h][c][reg];
                if (grow < M) C[(size_t)grow * N + gcol] = __float2half(val);
                ps[reg] += val * av;
                pd[reg] += val * dv;
            }
        }
#pragma unroll
        for (int off = 1; off < 16; off <<= 1) {
#pragma unroll
            for (int reg = 0; reg < 4; ++reg) {
                ps[reg] += __shfl_xor(ps[reg], off, 64);
                pd[reg] += __shfl_xor(pd[reg], off, 64);
            }
        }
        if (l16 == 0) {
#pragma unroll
            for (int reg = 0; reg < 4; ++reg) {
                int grow = rowBase + wv * 16 + q * 4 + reg;
                if (grow < M) {
                    as_out[grow * NH + h] = ps[reg];
                    ad_out[grow * NH + h] = pd[reg];
                }
            }
        }
    }
}

// ---------------- fused softmax + weighted aggregate ----------------
// wave per (node,head), HEAD-MAJOR grid. Fast path (deg<=64): lane=edge computes
// max/exp/sum; w,j parked in per-wave LDS (same-wave RAW -> no barrier).
// Accumulate: lane = es*8+cg (8 edge-sublanes x 8 channel-groups), 16B gathers.
template<int NH, bool RELU>
__global__ __launch_bounds__(256) void attn_agg(const int* __restrict__ row_ptr,
                                                const int* __restrict__ esrc,
                                                const __half* __restrict__ hf,  // [N][NH*64]
                                                const float* __restrict__ a_src, // [N][NH]
                                                const float* __restrict__ a_dst, // [N][NH]
                                                const float* __restrict__ bias,  // [NH*64]
                                                __half* __restrict__ zout) {     // [N][NH*64]
    __shared__ float wbuf[4][64];
    __shared__ int jbuf[4][64];
    int wid = (blockIdx.x * 256 + threadIdx.x) >> 6;
    int lane = threadIdx.x & 63;
    int wv = threadIdx.x >> 6;
    if (wid >= N_NODES * NH) return;
    int h = wid / N_NODES; // head-major: per-phase gather footprint ~3.8MB
    int node = wid - h * N_NODES;
    int start = row_ptr[node], end = row_ptr[node + 1];
    int deg = end - start;
    float adst = a_dst[node * NH + h];
    int es = lane >> 3, cg = lane & 7;
    const int RS = NH * 64;
    const __half* hbase = hf + h * 64 + cg * 8;
    float acc[8] = {};
    float r;
    if (deg <= 64) {
        int j = 0;
        float e = -1e30f;
        if (lane < deg) {
            j = esrc[start + lane];
            e = leaky(a_src[j * NH + h] + adst);
        }
        float m = e;
#pragma unroll
        for (int off = 1; off < 64; off <<= 1)
            m = fmaxf(m, __shfl_xor(m, off, 64));
        float ex = (lane < deg) ? __expf(e - m) : 0.f;
        float s = ex;
#pragma unroll
        for (int off = 1; off < 64; off <<= 1)
            s += __shfl_xor(s, off, 64);
        wbuf[wv][lane] = ex;
        jbuf[wv][lane] = j;
        r = 1.f / (s + 1e-16f);
        for (int k0 = 0; k0 < deg; k0 += 8) {
            int kk = k0 + es;
            bool ok = kk < deg;
            float wgt = ok ? wbuf[wv][kk] : 0.f;
            int j2 = jbuf[wv][ok ? kk : 0];
            float4 v = *(const float4*)(hbase + (size_t)j2 * RS);
            const __half2* pv = (const __half2*)&v;
#pragma unroll
            for (int i = 0; i < 4; ++i) {
                float2 f = __half22float2(pv[i]);
                acc[2 * i]     += wgt * f.x;
                acc[2 * i + 1] += wgt * f.y;
            }
        }
    } else { // rare: deg > 64 — strided recompute path (correctness)
        float m = -1e30f;
        for (int k = start + lane; k < end; k += 64)
            m = fmaxf(m, leaky(a_src[esrc[k] * NH + h] + adst));
#pragma unroll
        for (int off = 1; off < 64; off <<= 1)
            m = fmaxf(m, __shfl_xor(m, off, 64));
        float s = 0.f;
        for (int k = start + lane; k < end; k += 64)
            s += __expf(leaky(a_src[esrc[k] * NH + h] + adst) - m);
#pragma unroll
        for (int off = 1; off < 64; off <<= 1)
            s += __shfl_xor(s, off, 64);
        r = 1.f / (s + 1e-16f);
        for (int k0 = start; k0 < end; k0 += 8) {
            int kk = k0 + es;
            bool ok = kk < end;
            int j2 = esrc[ok ? kk : start];
            float wgt = ok ? __expf(leaky(a_src[j2 * NH + h] + adst) - m) : 0.f;
            float4 v = *(const float4*)(hbase + (size_t)j2 * RS);
            const __half2* pv = (const __half2*)&v;
#pragma unroll
            for (int i = 0; i < 4; ++i) {
                float2 f = __half22float2(pv[i]);
                acc[2 * i]     += wgt * f.x;
                acc[2 * i + 1] += wgt * f.y;
            }
        }
    }
#pragma unroll
    for (int off = 8; off < 64; off <<= 1)
#pragma unroll
        for (int i = 0; i < 8; ++i)
            acc[i] += __shfl_xor(acc[i], off, 64);
    if (es == 0) {
        const float* bb = bias + h * 64 + cg * 8;
        union { float4 f; __half2 hh[4]; } pk;
#pragma unroll
        for (int i = 0; i < 4; ++i) {
            float lo = acc[2 * i] * r + bb[2 * i];
            float hi = acc[2 * i + 1] * r + bb[2 * i + 1];
            if (RELU) { lo = fmaxf(lo, 0.f); hi = fmaxf(hi, 0.f); }
            pk.hh[i] = __floats2half2_rn(lo, hi);
        }
        *(float4*)(zout + (size_t)node * RS + h * 64 + cg * 8) = pk.f;
    }
}

// ---------------- decode: 8 lanes per edge, 16B fp16 loads ----------------
__global__ __launch_bounds__(256) void decode8(const int* __restrict__ pos,
                                               const int* __restrict__ neg,
                                               const __half* __restrict__ z2,
                                               float* __restrict__ out) {
    int t = blockIdx.x * 256 + threadIdx.x;
    int e = t >> 3;
    int lc = t & 7;
    if (e >= 2 * PE_CNT) return;
    int a, b;
    if (e < PE_CNT) { a = pos[e]; b = pos[PE_CNT + e]; }
    else { int k = e - PE_CNT; a = neg[k]; b = neg[PE_CNT + k]; }
    union U { float4 f; __half2 h[4]; } ua, ub;
    ua.f = *(const float4*)(z2 + (size_t)a * OUT_CH + lc * 8);
    ub.f = *(const float4*)(z2 + (size_t)b * OUT_CH + lc * 8);
    float v = 0.f;
#pragma unroll
    for (int i = 0; i < 4; ++i) {
        float2 fa = __half22float2(ua.h[i]);
        float2 fb = __half22float2(ub.h[i]);
        v += fa.x * fb.x + fa.y * fb.y;
    }
#pragma unroll
    for (int off = 1; off < 8; off <<= 1)
        v += __shfl_xor(v, off, 64);
    if (lc == 0) out[e] = v;
}

extern "C" void kernel_launch(void* const* d_in, const int* in_sizes, int n_in,
                              void* d_out, int out_size, void* d_ws, size_t ws_size,
                              hipStream_t stream) {
    const float* x        = (const float*)d_in[0];
    const int* edge_index = (const int*)d_in[1];
    const int* pos_ei     = (const int*)d_in[2];
    const int* neg_ei     = (const int*)d_in[3];
    const float* W1       = (const float*)d_in[4];
    const float* att_src1 = (const float*)d_in[5];
    const float* att_dst1 = (const float*)d_in[6];
    const float* b1       = (const float*)d_in[7];
    const float* W2       = (const float*)d_in[8];
    const float* att_src2 = (const float*)d_in[9];
    const float* att_dst2 = (const float*)d_in[10];
    const float* b2       = (const float*)d_in[11];
    float* out            = (float*)d_out;

    char* ws = (char*)d_ws;
    size_t off = 0;
    auto alloc = [&](size_t bytes) -> void* {
        void* p = ws + off;
        off = (off + bytes + 255) & ~(size_t)255;
        return p;
    };
    __half* h1    = (__half*)alloc(sizeof(__half) * (size_t)N_NODES * D1);
    __half* z1    = (__half*)alloc(sizeof(__half) * (size_t)N_NODES * D1);
    __half* h2    = (__half*)alloc(sizeof(__half) * (size_t)N_NODES * OUT_CH);
    __half* z2    = (__half*)alloc(sizeof(__half) * (size_t)N_NODES * OUT_CH);
    __half* Wt1   = (__half*)alloc(sizeof(__half) * (size_t)D1 * IN_CH);   // [320][128]
    __half* Wt2   = (__half*)alloc(sizeof(__half) * (size_t)OUT_CH * D1);  // [64][320]
    float* a_src1 = (float*)alloc(sizeof(float) * (size_t)N_NODES * HEADS1);
    float* a_dst1 = (float*)alloc(sizeof(float) * (size_t)N_NODES * HEADS1);
    float* a_src2 = (float*)alloc(sizeof(float) * (size_t)N_NODES);
    float* a_dst2 = (float*)alloc(sizeof(float) * (size_t)N_NODES);
    int* cnt      = (int*)alloc(sizeof(int) * (size_t)2 * N_NODES);
    int* cursor   = cnt + N_NODES;
    int* row_ptr  = (int*)alloc(sizeof(int) * (N_NODES + 1));
    int* esrc     = (int*)alloc(sizeof(int) * (size_t)N_EDGES_SL);

    // CSR build (shared by both GAT layers)
    zero_i32<<<(2 * N_NODES + 255) / 256, 256, 0, stream>>>(cnt, 2 * N_NODES);
    count_dst<<<(N_EDGES_SL + 255) / 256, 256, 0, stream>>>(edge_index, cnt);
    scan_csr<<<1, 1024, 0, stream>>>(cnt, row_ptr);
    scatter_edges<<<(N_EDGES_SL + 255) / 256, 256, 0, stream>>>(edge_index, row_ptr, cursor, esrc);

    // weight transpose+cast
    prep_wt<<<(IN_CH * D1 + 255) / 256, 256, 0, stream>>>(W1, Wt1, IN_CH, D1);
    prep_wt<<<(D1 * OUT_CH + 255) / 256, 256, 0, stream>>>(W2, Wt2, D1, OUT_CH);

    // layer 1: MFMA GEMM (fp16 out) + fused scores; fused softmax-aggregate
    gemm_mfma_att<HEADS1, float><<<(N_NODES + 63) / 64, 256, 0, stream>>>(
        x, Wt1, h1, N_NODES, IN_CH, att_src1, att_dst1, a_src1, a_dst1);
    attn_agg<HEADS1, true><<<(N_NODES * HEADS1 + 3) / 4, 256, 0, stream>>>(
        row_ptr, esrc, h1, a_src1, a_dst1, b1, z1);

    // layer 2
    gemm_mfma_att<1, __half><<<(N_NODES + 63) / 64, 256, 0, stream>>>(
        z1, Wt2, h2, N_NODES, D1, att_src2, att_dst2, a_src2, a_dst2);
    attn_agg<1, false><<<(N_NODES + 3) / 4, 256, 0, stream>>>(
        row_ptr, esrc, h2, a_src2, a_dst2, b2, z2);

    // decode
    decode8<<<(2 * PE_CNT * 8 + 255) / 256, 256, 0, stream>>>(pos_ei, neg_ei, z2, out);

    (void)in_sizes; (void)n_in; (void)out_size; (void)ws_size;
}

// Round 6
// 287.872 us; speedup vs baseline: 1.6335x; 1.0814x over previous
//
#include <hip/hip_runtime.h>
#include <hip/hip_fp16.h>
#include <cstdint>
#include <cstddef>
#include <type_traits>

#define N_NODES 30000
#define N_EDGES 480000
#define N_EDGES_SL (N_EDGES + N_NODES) // 510000
#define IN_CH 128
#define HEADS1 5
#define C1 64
#define D1 (HEADS1 * C1) // 320
#define OUT_CH 64
#define PE_CNT 100000
#define NEG_SLOPE 0.2f

typedef _Float16 f16x8 __attribute__((ext_vector_type(8)));
typedef float fx4 __attribute__((ext_vector_type(4)));

static __device__ __forceinline__ float leaky(float x) {
    return x > 0.f ? x : NEG_SLOPE * x;
}

// ---------------- CSR build (counting sort by dst) ----------------
__global__ void count_dst(const int* __restrict__ edge, int* __restrict__ cnt) {
    int e = blockIdx.x * blockDim.x + threadIdx.x;
    if (e >= N_EDGES_SL) return;
    int d = (e < N_EDGES) ? edge[N_EDGES + e] : (e - N_EDGES);
    atomicAdd(&cnt[d], 1);
}

// single block, 1024 threads, 30 coalesced chunk-scans with running carry
__global__ __launch_bounds__(1024) void scan_csr(const int* __restrict__ cnt,
                                                 int* __restrict__ row_ptr) {
    __shared__ int wsum[16];
    __shared__ int wexc[16];
    __shared__ int chtot;
    int t = threadIdx.x, lane = t & 63, wv = t >> 6;
    int carry = 0;
    for (int base = 0; base < N_NODES; base += 1024) {
        int i = base + t;
        int v = (i < N_NODES) ? cnt[i] : 0;
        int inc = v;
#pragma unroll
        for (int off = 1; off < 64; off <<= 1) {
            int u = __shfl_up(inc, off, 64);
            if (lane >= off) inc += u;
        }
        if (lane == 63) wsum[wv] = inc;
        __syncthreads();
        if (wv == 0) {
            int val = (lane < 16) ? wsum[lane] : 0;
            int iv = val;
#pragma unroll
            for (int off = 1; off < 16; off <<= 1) {
                int u = __shfl_up(iv, off, 64);
                if (lane >= off) iv += u;
            }
            if (lane < 16) wexc[lane] = iv - val;
            if (lane == 15) chtot = iv;
        }
        __syncthreads();
        if (i < N_NODES) row_ptr[i] = carry + wexc[wv] + inc - v;
        carry += chtot;
    }
    if (t == 0) row_ptr[N_NODES] = carry;
}

__global__ void scatter_edges(const int* __restrict__ edge, const int* __restrict__ row_ptr,
                              int* __restrict__ cursor, int* __restrict__ esrc) {
    int e = blockIdx.x * blockDim.x + threadIdx.x;
    if (e >= N_EDGES_SL) return;
    int s, d;
    if (e < N_EDGES) { s = edge[e]; d = edge[N_EDGES + e]; }
    else { s = e - N_EDGES; d = s; }
    int pos = row_ptr[d] + atomicAdd(&cursor[d], 1);
    esrc[pos] = s;
}

// ---------------- weight prep (both): W[K][N] fp32 -> Wt[N][K] fp16 ----------------
__global__ void prep_wt2x(const float* __restrict__ W1, __half* __restrict__ Wt1,
                          const float* __restrict__ W2, __half* __restrict__ Wt2) {
    int idx = blockIdx.x * blockDim.x + threadIdx.x;
    const int T1 = IN_CH * D1;
    const int T2 = D1 * OUT_CH;
    if (idx < T1) {
        int k = idx / D1, n = idx - k * D1;
        Wt1[(size_t)n * IN_CH + k] = __float2half(W1[idx]);
    } else if (idx < T1 + T2) {
        int i2 = idx - T1;
        int k = i2 / OUT_CH, n = i2 - k * OUT_CH;
        Wt2[(size_t)n * D1 + k] = __float2half(W2[i2]);
    }
}

// ---------------- MFMA fp16 GEMM + fused attention-score epilogue ----------------
// C[M, NH*64] (fp16) = A[M,K] @ W, W given as Wt[N][K] fp16 (pre-transposed).
// MFMA 16x16x32_f16 layouts (HW-verified):
//   A: lane holds A[m=lane&15][k=quad*8+j]; B: lane holds B[k=quad*8+j][n=lane&15]
//   D: lane reg holds D[row=quad*4+reg][col=lane&15]
template<int NH, typename AT>
__global__ __launch_bounds__(256) void gemm_mfma_att(const AT* __restrict__ A,
                                                     const __half* __restrict__ Wt,
                                                     __half* __restrict__ C,
                                                     int M, int K,
                                                     const float* __restrict__ att_src,
                                                     const float* __restrict__ att_dst,
                                                     float* __restrict__ as_out,
                                                     float* __restrict__ ad_out) {
    const int N = NH * 64;
    __shared__ __align__(16) __half As[64][40]; // 32 k + 8 pad halves
    int tid = threadIdx.x;
    int wv = tid >> 6, lane = tid & 63;
    int q = lane >> 4, l16 = lane & 15;
    int rowBase = blockIdx.x * 64;

    fx4 zero4 = {0.f, 0.f, 0.f, 0.f};
    fx4 acc[NH][4];
#pragma unroll
    for (int h = 0; h < NH; ++h)
#pragma unroll
        for (int c = 0; c < 4; ++c) acc[h][c] = zero4;

    int ar = tid >> 2;       // staging row 0..63
    int ak = (tid & 3) * 8;  // staging k offset 0,8,16,24

    for (int kk = 0; kk < K; kk += 32) {
        {
            int grow = rowBase + ar;
            if constexpr (std::is_same<AT, float>::value) {
                float4 v0 = make_float4(0.f, 0.f, 0.f, 0.f), v1 = v0;
                if (grow < M) {
                    const float4* s = (const float4*)(A + (size_t)grow * K + kk + ak);
                    v0 = s[0]; v1 = s[1];
                }
                f16x8 hv;
                hv[0] = (_Float16)v0.x; hv[1] = (_Float16)v0.y;
                hv[2] = (_Float16)v0.z; hv[3] = (_Float16)v0.w;
                hv[4] = (_Float16)v1.x; hv[5] = (_Float16)v1.y;
                hv[6] = (_Float16)v1.z; hv[7] = (_Float16)v1.w;
                *(f16x8*)(&As[ar][ak]) = hv;
            } else {
                float4 v = make_float4(0.f, 0.f, 0.f, 0.f);
                if (grow < M)
                    v = *(const float4*)((const __half*)A + (size_t)grow * K + kk + ak);
                *(float4*)(&As[ar][ak]) = v;
            }
        }
        __syncthreads();
        f16x8 af = *(const f16x8*)(&As[wv * 16 + l16][q * 8]);
#pragma unroll
        for (int h = 0; h < NH; ++h) {
#pragma unroll
            for (int c = 0; c < 4; ++c) {
                int col = h * 64 + c * 16 + l16;
                f16x8 bf = *(const f16x8*)(Wt + (size_t)col * K + kk + q * 8);
                acc[h][c] = __builtin_amdgcn_mfma_f32_16x16x32_f16(af, bf, acc[h][c], 0, 0, 0);
            }
        }
        __syncthreads();
    }
#pragma unroll
    for (int h = 0; h < NH; ++h) {
        float ps[4] = {0.f, 0.f, 0.f, 0.f};
        float pd[4] = {0.f, 0.f, 0.f, 0.f};
#pragma unroll
        for (int c = 0; c < 4; ++c) {
            int gcol = h * 64 + c * 16 + l16;
            float av = att_src[gcol];
            float dv = att_dst[gcol];
#pragma unroll
            for (int reg = 0; reg < 4; ++reg) {
                int grow = rowBase + wv * 16 + q * 4 + reg;
                float val = acc[h][c][reg];
                if (grow < M) C[(size_t)grow * N + gcol] = __float2half(val);
                ps[reg] += val * av;
                pd[reg] += val * dv;
            }
        }
#pragma unroll
        for (int off = 1; off < 16; off <<= 1) {
#pragma unroll
            for (int reg = 0; reg < 4; ++reg) {
                ps[reg] += __shfl_xor(ps[reg], off, 64);
                pd[reg] += __shfl_xor(pd[reg], off, 64);
            }
        }
        if (l16 == 0) {
#pragma unroll
            for (int reg = 0; reg < 4; ++reg) {
                int grow = rowBase + wv * 16 + q * 4 + reg;
                if (grow < M) {
                    as_out[grow * NH + h] = ps[reg];
                    ad_out[grow * NH + h] = pd[reg];
                }
            }
        }
    }
}

// ---------------- fused softmax + weighted aggregate ----------------
// wave per (node,head), HEAD-MAJOR grid.
// No max-subtract: inputs are bounded (|e| ~ 5 << 88), exp(e)/sum(exp(e)) is
// mathematically identical to the max-shifted form — saves 6 shuffle steps of
// serial chain per wave.
// Fast path (deg<=64): lane=edge computes exp; w,j parked in per-wave LDS
// (same-wave RAW, no barrier). Accumulate: lane = es*8+cg, TWO independent
// 16B gathers in flight per iteration. Reduction: LDS transpose (pad-9 stride,
// 2-way conflicts only) -> all 64 lanes do bias/relu/store epilogue.
template<int NH, bool RELU>
__global__ __launch_bounds__(256) void attn_agg(const int* __restrict__ row_ptr,
                                                const int* __restrict__ esrc,
                                                const __half* __restrict__ hf,   // [N][NH*64]
                                                const float* __restrict__ a_src, // [N][NH]
                                                const float* __restrict__ a_dst, // [N][NH]
                                                const float* __restrict__ bias,  // [NH*64]
                                                __half* __restrict__ zout) {     // [N][NH*64]
    __shared__ float wbuf[4][64];
    __shared__ int jbuf[4][64];
    __shared__ float red[4][64 * 9 + 8]; // [ch]*9+es pad layout
    int wid = (blockIdx.x * 256 + threadIdx.x) >> 6;
    int lane = threadIdx.x & 63;
    int wv = threadIdx.x >> 6;
    if (wid >= N_NODES * NH) return;
    int h = wid / N_NODES; // head-major: per-phase gather footprint ~3.8MB
    int node = wid - h * N_NODES;
    int start = row_ptr[node], end = row_ptr[node + 1];
    int deg = end - start;
    float adst = a_dst[node * NH + h];
    int es = lane >> 3, cg = lane & 7;
    const int RS = NH * 64;
    const __half* hbase = hf + h * 64 + cg * 8;
    float acc[8] = {};
    float r;
    if (deg <= 64) {
        int j = 0;
        float ex = 0.f;
        if (lane < deg) {
            j = esrc[start + lane];
            ex = __expf(leaky(a_src[j * NH + h] + adst));
        }
        float s = ex;
#pragma unroll
        for (int off = 1; off < 64; off <<= 1)
            s += __shfl_xor(s, off, 64);
        wbuf[wv][lane] = ex;
        jbuf[wv][lane] = j;
        r = 1.f / (s + 1e-16f);
        for (int k0 = 0; k0 < deg; k0 += 16) {
            int kA = k0 + es, kB = k0 + 8 + es;
            bool okA = kA < deg, okB = kB < deg;
            float wA = okA ? wbuf[wv][kA] : 0.f;
            float wB = okB ? wbuf[wv][kB] : 0.f;
            int jA = jbuf[wv][okA ? kA : 0];
            int jB = jbuf[wv][okB ? kB : 0];
            float4 vA = *(const float4*)(hbase + (size_t)jA * RS);
            float4 vB = *(const float4*)(hbase + (size_t)jB * RS);
            const __half2* pA = (const __half2*)&vA;
            const __half2* pB = (const __half2*)&vB;
#pragma unroll
            for (int i = 0; i < 4; ++i) {
                float2 fA = __half22float2(pA[i]);
                float2 fB = __half22float2(pB[i]);
                acc[2 * i]     += wA * fA.x + wB * fB.x;
                acc[2 * i + 1] += wA * fA.y + wB * fB.y;
            }
        }
    } else { // rare: deg > 64 — strided recompute path
        float s = 0.f;
        for (int k = start + lane; k < end; k += 64)
            s += __expf(leaky(a_src[esrc[k] * NH + h] + adst));
#pragma unroll
        for (int off = 1; off < 64; off <<= 1)
            s += __shfl_xor(s, off, 64);
        r = 1.f / (s + 1e-16f);
        for (int k0 = start; k0 < end; k0 += 16) {
            int kA = k0 + es, kB = k0 + 8 + es;
            bool okA = kA < end, okB = kB < end;
            int jA = esrc[okA ? kA : start];
            int jB = esrc[okB ? kB : start];
            float wA = okA ? __expf(leaky(a_src[jA * NH + h] + adst)) : 0.f;
            float wB = okB ? __expf(leaky(a_src[jB * NH + h] + adst)) : 0.f;
            float4 vA = *(const float4*)(hbase + (size_t)jA * RS);
            float4 vB = *(const float4*)(hbase + (size_t)jB * RS);
            const __half2* pA = (const __half2*)&vA;
            const __half2* pB = (const __half2*)&vB;
#pragma unroll
            for (int i = 0; i < 4; ++i) {
                float2 fA = __half22float2(pA[i]);
                float2 fB = __half22float2(pB[i]);
                acc[2 * i]     += wA * fA.x + wB * fB.x;
                acc[2 * i + 1] += wA * fA.y + wB * fB.y;
            }
        }
    }
    // LDS transpose reduction over the 8 edge-sublanes (same wave, no barrier)
#pragma unroll
    for (int i = 0; i < 8; ++i)
        red[wv][(cg * 8 + i) * 9 + es] = acc[i];
    float tot = 0.f;
#pragma unroll
    for (int e2 = 0; e2 < 8; ++e2)
        tot += red[wv][lane * 9 + e2];
    float o = tot * r + bias[h * 64 + lane];
    if (RELU) o = fmaxf(o, 0.f);
    zout[(size_t)node * RS + h * 64 + lane] = __float2half(o);
}

// ---------------- decode: 8 lanes per edge, 16B fp16 loads ----------------
__global__ __launch_bounds__(256) void decode8(const int* __restrict__ pos,
                                               const int* __restrict__ neg,
                                               const __half* __restrict__ z2,
                                               float* __restrict__ out) {
    int t = blockIdx.x * 256 + threadIdx.x;
    int e = t >> 3;
    int lc = t & 7;
    if (e >= 2 * PE_CNT) return;
    int a, b;
    if (e < PE_CNT) { a = pos[e]; b = pos[PE_CNT + e]; }
    else { int k = e - PE_CNT; a = neg[k]; b = neg[PE_CNT + k]; }
    union U { float4 f; __half2 h[4]; } ua, ub;
    ua.f = *(const float4*)(z2 + (size_t)a * OUT_CH + lc * 8);
    ub.f = *(const float4*)(z2 + (size_t)b * OUT_CH + lc * 8);
    float v = 0.f;
#pragma unroll
    for (int i = 0; i < 4; ++i) {
        float2 fa = __half22float2(ua.h[i]);
        float2 fb = __half22float2(ub.h[i]);
        v += fa.x * fb.x + fa.y * fb.y;
    }
#pragma unroll
    for (int off = 1; off < 8; off <<= 1)
        v += __shfl_xor(v, off, 64);
    if (lc == 0) out[e] = v;
}

extern "C" void kernel_launch(void* const* d_in, const int* in_sizes, int n_in,
                              void* d_out, int out_size, void* d_ws, size_t ws_size,
                              hipStream_t stream) {
    const float* x        = (const float*)d_in[0];
    const int* edge_index = (const int*)d_in[1];
    const int* pos_ei     = (const int*)d_in[2];
    const int* neg_ei     = (const int*)d_in[3];
    const float* W1       = (const float*)d_in[4];
    const float* att_src1 = (const float*)d_in[5];
    const float* att_dst1 = (const float*)d_in[6];
    const float* b1       = (const float*)d_in[7];
    const float* W2       = (const float*)d_in[8];
    const float* att_src2 = (const float*)d_in[9];
    const float* att_dst2 = (const float*)d_in[10];
    const float* b2       = (const float*)d_in[11];
    float* out            = (float*)d_out;

    char* ws = (char*)d_ws;
    size_t off = 0;
    auto alloc = [&](size_t bytes) -> void* {
        void* p = ws + off;
        off = (off + bytes + 255) & ~(size_t)255;
        return p;
    };
    __half* h1    = (__half*)alloc(sizeof(__half) * (size_t)N_NODES * D1);
    __half* z1    = (__half*)alloc(sizeof(__half) * (size_t)N_NODES * D1);
    __half* h2    = (__half*)alloc(sizeof(__half) * (size_t)N_NODES * OUT_CH);
    __half* z2    = (__half*)alloc(sizeof(__half) * (size_t)N_NODES * OUT_CH);
    __half* Wt1   = (__half*)alloc(sizeof(__half) * (size_t)D1 * IN_CH);   // [320][128]
    __half* Wt2   = (__half*)alloc(sizeof(__half) * (size_t)OUT_CH * D1);  // [64][320]
    float* a_src1 = (float*)alloc(sizeof(float) * (size_t)N_NODES * HEADS1);
    float* a_dst1 = (float*)alloc(sizeof(float) * (size_t)N_NODES * HEADS1);
    float* a_src2 = (float*)alloc(sizeof(float) * (size_t)N_NODES);
    float* a_dst2 = (float*)alloc(sizeof(float) * (size_t)N_NODES);
    int* cnt      = (int*)alloc(sizeof(int) * (size_t)2 * N_NODES);
    int* cursor   = cnt + N_NODES;
    int* row_ptr  = (int*)alloc(sizeof(int) * (N_NODES + 1));
    int* esrc     = (int*)alloc(sizeof(int) * (size_t)N_EDGES_SL);

    // CSR build (shared by both GAT layers)
    hipMemsetAsync(cnt, 0, sizeof(int) * (size_t)2 * N_NODES, stream);
    count_dst<<<(N_EDGES_SL + 255) / 256, 256, 0, stream>>>(edge_index, cnt);
    scan_csr<<<1, 1024, 0, stream>>>(cnt, row_ptr);
    scatter_edges<<<(N_EDGES_SL + 255) / 256, 256, 0, stream>>>(edge_index, row_ptr, cursor, esrc);

    // weight transpose+cast (both in one launch)
    prep_wt2x<<<(IN_CH * D1 + D1 * OUT_CH + 255) / 256, 256, 0, stream>>>(W1, Wt1, W2, Wt2);

    // layer 1: MFMA GEMM (fp16 out) + fused scores; fused softmax-aggregate
    gemm_mfma_att<HEADS1, float><<<(N_NODES + 63) / 64, 256, 0, stream>>>(
        x, Wt1, h1, N_NODES, IN_CH, att_src1, att_dst1, a_src1, a_dst1);
    attn_agg<HEADS1, true><<<(N_NODES * HEADS1 + 3) / 4, 256, 0, stream>>>(
        row_ptr, esrc, h1, a_src1, a_dst1, b1, z1);

    // layer 2
    gemm_mfma_att<1, __half><<<(N_NODES + 63) / 64, 256, 0, stream>>>(
        z1, Wt2, h2, N_NODES, D1, att_src2, att_dst2, a_src2, a_dst2);
    attn_agg<1, false><<<(N_NODES + 3) / 4, 256, 0, stream>>>(
        row_ptr, esrc, h2, a_src2, a_dst2, b2, z2);

    // decode
    decode8<<<(2 * PE_CNT * 8 + 255) / 256, 256, 0, stream>>>(pos_ei, neg_ei, z2, out);

    (void)in_sizes; (void)n_in; (void)out_size; (void)ws_size;
}

// Round 7
// 284.066 us; speedup vs baseline: 1.6554x; 1.0134x over previous
//
#include <hip/hip_runtime.h>
#include <hip/hip_fp16.h>
#include <cstdint>
#include <cstddef>
#include <type_traits>

#define N_NODES 30000
#define N_EDGES 480000
#define N_EDGES_SL (N_EDGES + N_NODES) // 510000
#define IN_CH 128
#define HEADS1 5
#define C1 64
#define D1 (HEADS1 * C1) // 320
#define OUT_CH 64
#define PE_CNT 100000
#define NEG_SLOPE 0.2f

typedef _Float16 f16x8 __attribute__((ext_vector_type(8)));
typedef _Float16 f16x2 __attribute__((ext_vector_type(2)));
typedef float fx4 __attribute__((ext_vector_type(4)));

#if defined(__has_builtin)
#if __has_builtin(__builtin_amdgcn_fdot2)
#define HAS_FDOT2 1
#endif
#endif

static __device__ __forceinline__ float leaky(float x) {
    return x > 0.f ? x : NEG_SLOPE * x;
}

// ---------------- CSR build (counting sort by dst) ----------------
__global__ void count_dst(const int* __restrict__ edge, int* __restrict__ cnt) {
    int e = blockIdx.x * blockDim.x + threadIdx.x;
    if (e >= N_EDGES_SL) return;
    int d = (e < N_EDGES) ? edge[N_EDGES + e] : (e - N_EDGES);
    atomicAdd(&cnt[d], 1);
}

// single block, 1024 threads, 30 coalesced chunk-scans with running carry
__global__ __launch_bounds__(1024) void scan_csr(const int* __restrict__ cnt,
                                                 int* __restrict__ row_ptr) {
    __shared__ int wsum[16];
    __shared__ int wexc[16];
    __shared__ int chtot;
    int t = threadIdx.x, lane = t & 63, wv = t >> 6;
    int carry = 0;
    for (int base = 0; base < N_NODES; base += 1024) {
        int i = base + t;
        int v = (i < N_NODES) ? cnt[i] : 0;
        int inc = v;
#pragma unroll
        for (int off = 1; off < 64; off <<= 1) {
            int u = __shfl_up(inc, off, 64);
            if (lane >= off) inc += u;
        }
        if (lane == 63) wsum[wv] = inc;
        __syncthreads();
        if (wv == 0) {
            int val = (lane < 16) ? wsum[lane] : 0;
            int iv = val;
#pragma unroll
            for (int off = 1; off < 16; off <<= 1) {
                int u = __shfl_up(iv, off, 64);
                if (lane >= off) iv += u;
            }
            if (lane < 16) wexc[lane] = iv - val;
            if (lane == 15) chtot = iv;
        }
        __syncthreads();
        if (i < N_NODES) row_ptr[i] = carry + wexc[wv] + inc - v;
        carry += chtot;
    }
    if (t == 0) row_ptr[N_NODES] = carry;
}

__global__ void scatter_edges(const int* __restrict__ edge, const int* __restrict__ row_ptr,
                              int* __restrict__ cursor, int* __restrict__ esrc) {
    int e = blockIdx.x * blockDim.x + threadIdx.x;
    if (e >= N_EDGES_SL) return;
    int s, d;
    if (e < N_EDGES) { s = edge[e]; d = edge[N_EDGES + e]; }
    else { s = e - N_EDGES; d = s; }
    int pos = row_ptr[d] + atomicAdd(&cursor[d], 1);
    esrc[pos] = s;
}

// ---------------- weight prep (both): W[K][N] fp32 -> Wt[N][K] fp16 ----------------
__global__ void prep_wt2x(const float* __restrict__ W1, __half* __restrict__ Wt1,
                          const float* __restrict__ W2, __half* __restrict__ Wt2) {
    int idx = blockIdx.x * blockDim.x + threadIdx.x;
    const int T1 = IN_CH * D1;
    const int T2 = D1 * OUT_CH;
    if (idx < T1) {
        int k = idx / D1, n = idx - k * D1;
        Wt1[(size_t)n * IN_CH + k] = __float2half(W1[idx]);
    } else if (idx < T1 + T2) {
        int i2 = idx - T1;
        int k = i2 / OUT_CH, n = i2 - k * OUT_CH;
        Wt2[(size_t)n * D1 + k] = __float2half(W2[i2]);
    }
}

// ---------------- barrier-free MFMA fp16 GEMM + fused attention scores ----------------
// One WAVE per 16 rows (30000 = 16*1875, no row guard). NO LDS, NO barriers:
// the mfma_f32_16x16x32_f16 A-fragment (lane holds A[m=lane&15][k=quad*8+j])
// is a direct contiguous 16B load when A is fp16, or 2x float4 + cvt when fp32.
// B from Wt[N][K] fp16 (L2-resident). D: lane reg holds D[row=quad*4+reg][col=lane&15].
// Scores written HEAD-MAJOR: as_out[h*N_NODES + row].
template<int NH, typename AT>
__global__ __launch_bounds__(64) void gemm_mfma_att(const AT* __restrict__ A,
                                                    const __half* __restrict__ Wt,
                                                    __half* __restrict__ C,
                                                    int K,
                                                    const float* __restrict__ att_src,
                                                    const float* __restrict__ att_dst,
                                                    float* __restrict__ as_out,
                                                    float* __restrict__ ad_out) {
    const int N = NH * 64;
    int lane = threadIdx.x;
    int q = lane >> 4, l16 = lane & 15;
    int rowBase = blockIdx.x * 16;
    int arow = rowBase + l16;

    fx4 zero4 = {0.f, 0.f, 0.f, 0.f};
    fx4 acc[NH][4];
#pragma unroll
    for (int h = 0; h < NH; ++h)
#pragma unroll
        for (int c = 0; c < 4; ++c) acc[h][c] = zero4;

    for (int kk = 0; kk < K; kk += 32) {
        f16x8 af;
        if constexpr (std::is_same<AT, float>::value) {
            const float4* s = (const float4*)(A + (size_t)arow * K + kk + q * 8);
            float4 v0 = s[0], v1 = s[1];
            af[0] = (_Float16)v0.x; af[1] = (_Float16)v0.y;
            af[2] = (_Float16)v0.z; af[3] = (_Float16)v0.w;
            af[4] = (_Float16)v1.x; af[5] = (_Float16)v1.y;
            af[6] = (_Float16)v1.z; af[7] = (_Float16)v1.w;
        } else {
            af = *(const f16x8*)((const __half*)A + (size_t)arow * K + kk + q * 8);
        }
#pragma unroll
        for (int h = 0; h < NH; ++h) {
#pragma unroll
            for (int c = 0; c < 4; ++c) {
                int col = h * 64 + c * 16 + l16;
                f16x8 bf = *(const f16x8*)(Wt + (size_t)col * K + kk + q * 8);
                acc[h][c] = __builtin_amdgcn_mfma_f32_16x16x32_f16(af, bf, acc[h][c], 0, 0, 0);
            }
        }
    }
#pragma unroll
    for (int h = 0; h < NH; ++h) {
        float ps[4] = {0.f, 0.f, 0.f, 0.f};
        float pd[4] = {0.f, 0.f, 0.f, 0.f};
#pragma unroll
        for (int c = 0; c < 4; ++c) {
            int gcol = h * 64 + c * 16 + l16;
            float av = att_src[gcol];
            float dv = att_dst[gcol];
#pragma unroll
            for (int reg = 0; reg < 4; ++reg) {
                int grow = rowBase + q * 4 + reg;
                float val = acc[h][c][reg];
                C[(size_t)grow * N + gcol] = __float2half(val);
                ps[reg] += val * av;
                pd[reg] += val * dv;
            }
        }
#pragma unroll
        for (int off = 1; off < 16; off <<= 1) {
#pragma unroll
            for (int reg = 0; reg < 4; ++reg) {
                ps[reg] += __shfl_xor(ps[reg], off, 64);
                pd[reg] += __shfl_xor(pd[reg], off, 64);
            }
        }
        if (l16 == 0) {
#pragma unroll
            for (int reg = 0; reg < 4; ++reg) {
                int grow = rowBase + q * 4 + reg;
                as_out[(size_t)h * N_NODES + grow] = ps[reg];
                ad_out[(size_t)h * N_NODES + grow] = pd[reg];
            }
        }
    }
}

// ---------------- fused softmax + weighted aggregate ----------------
// wave per (node,head), HEAD-MAJOR grid; a_src/a_dst HEAD-MAJOR [h][N] so the
// random per-edge score reads hit a compact 120KB region per head phase.
// No max-subtract (inputs bounded, exp(e)/sum mathematically identical).
// Fast path (deg<=64): lane=edge computes exp; w,j in per-wave LDS (same-wave
// RAW, no barrier). Accumulate: lane = es*8+cg, 2 independent 16B gathers/iter.
// Reduction: LDS transpose (pad-9) -> all 64 lanes do epilogue.
template<int NH, bool RELU>
__global__ __launch_bounds__(256) void attn_agg(const int* __restrict__ row_ptr,
                                                const int* __restrict__ esrc,
                                                const __half* __restrict__ hf,   // [N][NH*64]
                                                const float* __restrict__ a_src, // [NH][N]
                                                const float* __restrict__ a_dst, // [NH][N]
                                                const float* __restrict__ bias,  // [NH*64]
                                                __half* __restrict__ zout) {     // [N][NH*64]
    __shared__ float wbuf[4][64];
    __shared__ int jbuf[4][64];
    __shared__ float red[4][64 * 9 + 8];
    int wid = (blockIdx.x * 256 + threadIdx.x) >> 6;
    int lane = threadIdx.x & 63;
    int wv = threadIdx.x >> 6;
    if (wid >= N_NODES * NH) return;
    int h = wid / N_NODES;
    int node = wid - h * N_NODES;
    int start = row_ptr[node], end = row_ptr[node + 1];
    int deg = end - start;
    const float* asrc_h = a_src + (size_t)h * N_NODES;
    float adst = a_dst[(size_t)h * N_NODES + node];
    int es = lane >> 3, cg = lane & 7;
    const int RS = NH * 64;
    const __half* hbase = hf + h * 64 + cg * 8;
    float acc[8] = {};
    float r;
    if (deg <= 64) {
        int j = 0;
        float ex = 0.f;
        if (lane < deg) {
            j = esrc[start + lane];
            ex = __expf(leaky(asrc_h[j] + adst));
        }
        float s = ex;
#pragma unroll
        for (int off = 1; off < 64; off <<= 1)
            s += __shfl_xor(s, off, 64);
        wbuf[wv][lane] = ex;
        jbuf[wv][lane] = j;
        r = 1.f / (s + 1e-16f);
        for (int k0 = 0; k0 < deg; k0 += 16) {
            int kA = k0 + es, kB = k0 + 8 + es;
            bool okA = kA < deg, okB = kB < deg;
            float wA = okA ? wbuf[wv][kA] : 0.f;
            float wB = okB ? wbuf[wv][kB] : 0.f;
            int jA = jbuf[wv][okA ? kA : 0];
            int jB = jbuf[wv][okB ? kB : 0];
            float4 vA = *(const float4*)(hbase + (size_t)jA * RS);
            float4 vB = *(const float4*)(hbase + (size_t)jB * RS);
            const __half2* pA = (const __half2*)&vA;
            const __half2* pB = (const __half2*)&vB;
#pragma unroll
            for (int i = 0; i < 4; ++i) {
                float2 fA = __half22float2(pA[i]);
                float2 fB = __half22float2(pB[i]);
                acc[2 * i]     += wA * fA.x + wB * fB.x;
                acc[2 * i + 1] += wA * fA.y + wB * fB.y;
            }
        }
    } else { // rare: deg > 64
        float s = 0.f;
        for (int k = start + lane; k < end; k += 64)
            s += __expf(leaky(asrc_h[esrc[k]] + adst));
#pragma unroll
        for (int off = 1; off < 64; off <<= 1)
            s += __shfl_xor(s, off, 64);
        r = 1.f / (s + 1e-16f);
        for (int k0 = start; k0 < end; k0 += 16) {
            int kA = k0 + es, kB = k0 + 8 + es;
            bool okA = kA < end, okB = kB < end;
            int jA = esrc[okA ? kA : start];
            int jB = esrc[okB ? kB : start];
            float wA = okA ? __expf(leaky(asrc_h[jA] + adst)) : 0.f;
            float wB = okB ? __expf(leaky(asrc_h[jB] + adst)) : 0.f;
            float4 vA = *(const float4*)(hbase + (size_t)jA * RS);
            float4 vB = *(const float4*)(hbase + (size_t)jB * RS);
            const __half2* pA = (const __half2*)&vA;
            const __half2* pB = (const __half2*)&vB;
#pragma unroll
            for (int i = 0; i < 4; ++i) {
                float2 fA = __half22float2(pA[i]);
                float2 fB = __half22float2(pB[i]);
                acc[2 * i]     += wA * fA.x + wB * fB.x;
                acc[2 * i + 1] += wA * fA.y + wB * fB.y;
            }
        }
    }
#pragma unroll
    for (int i = 0; i < 8; ++i)
        red[wv][(cg * 8 + i) * 9 + es] = acc[i];
    float tot = 0.f;
#pragma unroll
    for (int e2 = 0; e2 < 8; ++e2)
        tot += red[wv][lane * 9 + e2];
    float o = tot * r + bias[h * 64 + lane];
    if (RELU) o = fmaxf(o, 0.f);
    zout[(size_t)node * RS + h * 64 + lane] = __float2half(o);
}

// ---------------- decode: 8 lanes per edge, 16B fp16 loads, v_dot2 ----------------
__global__ __launch_bounds__(256) void decode8(const int* __restrict__ pos,
                                               const int* __restrict__ neg,
                                               const __half* __restrict__ z2,
                                               float* __restrict__ out) {
    int t = blockIdx.x * 256 + threadIdx.x;
    int e = t >> 3;
    int lc = t & 7;
    if (e >= 2 * PE_CNT) return;
    int a, b;
    if (e < PE_CNT) { a = pos[e]; b = pos[PE_CNT + e]; }
    else { int k = e - PE_CNT; a = neg[k]; b = neg[PE_CNT + k]; }
    union U { float4 f; f16x2 h[4]; __half2 hh[4]; } ua, ub;
    ua.f = *(const float4*)(z2 + (size_t)a * OUT_CH + lc * 8);
    ub.f = *(const float4*)(z2 + (size_t)b * OUT_CH + lc * 8);
    float v = 0.f;
#pragma unroll
    for (int i = 0; i < 4; ++i) {
#ifdef HAS_FDOT2
        v = __builtin_amdgcn_fdot2(ua.h[i], ub.h[i], v, false);
#else
        float2 fa = __half22float2(ua.hh[i]);
        float2 fb = __half22float2(ub.hh[i]);
        v += fa.x * fb.x + fa.y * fb.y;
#endif
    }
#pragma unroll
    for (int off = 1; off < 8; off <<= 1)
        v += __shfl_xor(v, off, 64);
    if (lc == 0) out[e] = v;
}

extern "C" void kernel_launch(void* const* d_in, const int* in_sizes, int n_in,
                              void* d_out, int out_size, void* d_ws, size_t ws_size,
                              hipStream_t stream) {
    const float* x        = (const float*)d_in[0];
    const int* edge_index = (const int*)d_in[1];
    const int* pos_ei     = (const int*)d_in[2];
    const int* neg_ei     = (const int*)d_in[3];
    const float* W1       = (const float*)d_in[4];
    const float* att_src1 = (const float*)d_in[5];
    const float* att_dst1 = (const float*)d_in[6];
    const float* b1       = (const float*)d_in[7];
    const float* W2       = (const float*)d_in[8];
    const float* att_src2 = (const float*)d_in[9];
    const float* att_dst2 = (const float*)d_in[10];
    const float* b2       = (const float*)d_in[11];
    float* out            = (float*)d_out;

    char* ws = (char*)d_ws;
    size_t off = 0;
    auto alloc = [&](size_t bytes) -> void* {
        void* p = ws + off;
        off = (off + bytes + 255) & ~(size_t)255;
        return p;
    };
    __half* h1    = (__half*)alloc(sizeof(__half) * (size_t)N_NODES * D1);
    __half* z1    = (__half*)alloc(sizeof(__half) * (size_t)N_NODES * D1);
    __half* h2    = (__half*)alloc(sizeof(__half) * (size_t)N_NODES * OUT_CH);
    __half* z2    = (__half*)alloc(sizeof(__half) * (size_t)N_NODES * OUT_CH);
    __half* Wt1   = (__half*)alloc(sizeof(__half) * (size_t)D1 * IN_CH);   // [320][128]
    __half* Wt2   = (__half*)alloc(sizeof(__half) * (size_t)OUT_CH * D1);  // [64][320]
    float* a_src1 = (float*)alloc(sizeof(float) * (size_t)N_NODES * HEADS1); // [h][N]
    float* a_dst1 = (float*)alloc(sizeof(float) * (size_t)N_NODES * HEADS1); // [h][N]
    float* a_src2 = (float*)alloc(sizeof(float) * (size_t)N_NODES);
    float* a_dst2 = (float*)alloc(sizeof(float) * (size_t)N_NODES);
    int* cnt      = (int*)alloc(sizeof(int) * (size_t)2 * N_NODES);
    int* cursor   = cnt + N_NODES;
    int* row_ptr  = (int*)alloc(sizeof(int) * (N_NODES + 1));
    int* esrc     = (int*)alloc(sizeof(int) * (size_t)N_EDGES_SL);

    // CSR build (shared by both GAT layers)
    hipMemsetAsync(cnt, 0, sizeof(int) * (size_t)2 * N_NODES, stream);
    count_dst<<<(N_EDGES_SL + 255) / 256, 256, 0, stream>>>(edge_index, cnt);
    scan_csr<<<1, 1024, 0, stream>>>(cnt, row_ptr);
    scatter_edges<<<(N_EDGES_SL + 255) / 256, 256, 0, stream>>>(edge_index, row_ptr, cursor, esrc);

    // weight transpose+cast (both in one launch)
    prep_wt2x<<<(IN_CH * D1 + D1 * OUT_CH + 255) / 256, 256, 0, stream>>>(W1, Wt1, W2, Wt2);

    // layer 1: barrier-free MFMA GEMM (fp16 out) + fused scores; fused softmax-aggregate
    gemm_mfma_att<HEADS1, float><<<N_NODES / 16, 64, 0, stream>>>(
        x, Wt1, h1, IN_CH, att_src1, att_dst1, a_src1, a_dst1);
    attn_agg<HEADS1, true><<<(N_NODES * HEADS1 + 3) / 4, 256, 0, stream>>>(
        row_ptr, esrc, h1, a_src1, a_dst1, b1, z1);

    // layer 2
    gemm_mfma_att<1, __half><<<N_NODES / 16, 64, 0, stream>>>(
        z1, Wt2, h2, D1, att_src2, att_dst2, a_src2, a_dst2);
    attn_agg<1, false><<<(N_NODES + 3) / 4, 256, 0, stream>>>(
        row_ptr, esrc, h2, a_src2, a_dst2, b2, z2);

    // decode
    decode8<<<(2 * PE_CNT * 8 + 255) / 256, 256, 0, stream>>>(pos_ei, neg_ei, z2, out);

    (void)in_sizes; (void)n_in; (void)out_size; (void)ws_size;
}